// Round 1
// baseline (4257.560 us; speedup 1.0000x reference)
//
#include <hip/hip_runtime.h>

#define NG 100000
#define NDR 10000
#define NDI 5000

__device__ __forceinline__ void atomAddF(float* p, float v) { unsafeAtomicAdd(p, v); }

__device__ __forceinline__ unsigned encf(float f) {
  unsigned u = __float_as_uint(f);
  return (u & 0x80000000u) ? ~u : (u | 0x80000000u);
}
__device__ __forceinline__ float decf(unsigned u) {
  return __uint_as_float((u & 0x80000000u) ? (u ^ 0x80000000u) : ~u);
}

// ---------------- degree / normalization ----------------
__global__ __launch_bounds__(256) void k_deg(const int* __restrict__ dst, int E,
                                             unsigned* __restrict__ deg) {
  int e = blockIdx.x * 256 + threadIdx.x;
  if (e < E) atomicAdd(&deg[dst[e]], 1u);
}

__global__ __launch_bounds__(256) void k_dis(const unsigned* __restrict__ deg,
                                             float* __restrict__ dis, int n) {
  int i = blockIdx.x * 256 + threadIdx.x;
  if (i < n) dis[i] = rsqrtf((float)deg[i] + 1.0f);
}

// ---------------- GEMM: X[M,128] @ W[128,N], col tile 128 ----------------
// MODE 0: v = dot * dis[row]; write to out0 (hh) AND out1 (acc)   (GCN)
// MODE 1: write dot to out0                                        (GAT hs)
template <int MODE>
__global__ __launch_bounds__(256) void k_gemm(const float* __restrict__ X,
                                              const float* __restrict__ W, int M, int N,
                                              float* __restrict__ out0,
                                              float* __restrict__ out1,
                                              const float* __restrict__ dis) {
  __shared__ float Ws[128][128];
  __shared__ float Xs[32][128];
  const int t = threadIdx.x;
  const int row0 = blockIdx.x * 32;
  const int col0 = blockIdx.y * 128;

  for (int i = t; i < 128 * 32; i += 256) {  // 4096 float4 = 128x128
    int k = i >> 5;
    int c4 = (i & 31) << 2;
    *(float4*)&Ws[k][c4] = *(const float4*)&W[(size_t)k * N + col0 + c4];
  }
  for (int i = t; i < 32 * 32; i += 256) {  // 1024 float4 = 32x128
    int r = i >> 5;
    int c4 = (i & 31) << 2;
    int gr = row0 + r;
    float4 v = make_float4(0.f, 0.f, 0.f, 0.f);
    if (gr < M) v = *(const float4*)&X[(size_t)gr * 128 + c4];
    *(float4*)&Xs[r][c4] = v;
  }
  __syncthreads();

  const int tc = (t & 15) * 8;
  const int tr = (t >> 4) * 2;
  float a[2][8];
#pragma unroll
  for (int r = 0; r < 2; r++)
#pragma unroll
    for (int j = 0; j < 8; j++) a[r][j] = 0.f;

  for (int k = 0; k < 128; k += 4) {
    float4 xa = *(const float4*)&Xs[tr][k];
    float4 xb = *(const float4*)&Xs[tr + 1][k];
    const float* xap = (const float*)&xa;
    const float* xbp = (const float*)&xb;
#pragma unroll
    for (int kk = 0; kk < 4; kk++) {
      float4 w0 = *(const float4*)&Ws[k + kk][tc];
      float4 w1 = *(const float4*)&Ws[k + kk][tc + 4];
      float x0 = xap[kk];
      float x1v = xbp[kk];
      a[0][0] += x0 * w0.x; a[0][1] += x0 * w0.y; a[0][2] += x0 * w0.z; a[0][3] += x0 * w0.w;
      a[0][4] += x0 * w1.x; a[0][5] += x0 * w1.y; a[0][6] += x0 * w1.z; a[0][7] += x0 * w1.w;
      a[1][0] += x1v * w0.x; a[1][1] += x1v * w0.y; a[1][2] += x1v * w0.z; a[1][3] += x1v * w0.w;
      a[1][4] += x1v * w1.x; a[1][5] += x1v * w1.y; a[1][6] += x1v * w1.z; a[1][7] += x1v * w1.w;
    }
  }

#pragma unroll
  for (int rr = 0; rr < 2; rr++) {
    int g = row0 + tr + rr;
    if (g < M) {
      float scale = 1.0f;
      if (MODE == 0) scale = dis[g];
      float4 v0 = make_float4(a[rr][0] * scale, a[rr][1] * scale, a[rr][2] * scale, a[rr][3] * scale);
      float4 v1 = make_float4(a[rr][4] * scale, a[rr][5] * scale, a[rr][6] * scale, a[rr][7] * scale);
      size_t base = (size_t)g * N + col0 + tc;
      *(float4*)&out0[base] = v0;
      *(float4*)&out0[base + 4] = v1;
      if (MODE == 0) {
        *(float4*)&out1[base] = v0;
        *(float4*)&out1[base + 4] = v1;
      }
    }
  }
}

// ---------------- GCN edge scatter: acc[d] += hh[s] ----------------
__global__ __launch_bounds__(256) void k_scatter(const int* __restrict__ src,
                                                 const int* __restrict__ dst, int E,
                                                 const float* __restrict__ hh,
                                                 float* __restrict__ acc) {
  int tid = blockIdx.x * 256 + threadIdx.x;
  int lane = tid & 31;
  int e = tid >> 5;
  int estep = (gridDim.x * 256) >> 5;
  for (; e < E; e += estep) {
    int s = src[e], d = dst[e];
    float4 v = *(const float4*)&hh[(size_t)s * 128 + lane * 4];
    float* p = &acc[(size_t)d * 128 + lane * 4];
    atomAddF(p + 0, v.x);
    atomAddF(p + 1, v.y);
    atomAddF(p + 2, v.z);
    atomAddF(p + 3, v.w);
  }
}

// ---------------- finalize layer1: x1 = relu(dis*acc + b) ----------------
__global__ __launch_bounds__(256) void k_fin1(const float* __restrict__ acc,
                                              const float* __restrict__ dis,
                                              const float* __restrict__ b,
                                              float* __restrict__ x1, int M) {
  int i = blockIdx.x * 256 + threadIdx.x;  // float4 index
  if (i >= M * 32) return;
  int row = i >> 5;
  int c4 = (i & 31) << 2;
  float dd = dis[row];
  float4 v = *(const float4*)&acc[(size_t)row * 128 + c4];
  float4 bb = *(const float4*)&b[c4];
  float4 r;
  r.x = fmaxf(dd * v.x + bb.x, 0.f);
  r.y = fmaxf(dd * v.y + bb.y, 0.f);
  r.z = fmaxf(dd * v.z + bb.z, 0.f);
  r.w = fmaxf(dd * v.w + bb.w, 0.f);
  *(float4*)&x1[(size_t)row * 128 + c4] = r;
}

// ---------------- make w_att: watt[i][slot] slot 0..3 drug, 4..7 disease ----------------
__global__ __launch_bounds__(256) void k_watt(const float* __restrict__ wd,
                                              const float* __restrict__ attd_d,
                                              const float* __restrict__ wc,
                                              const float* __restrict__ attd_c,
                                              float* __restrict__ watt) {
  int t = threadIdx.x;
  for (int slot = t; slot < 1024; slot += 256) {
    int i = slot >> 3, s8 = slot & 7;
    const float* W = (s8 < 4) ? wd : wc;
    const float* A = (s8 < 4) ? attd_d : attd_c;
    int h = s8 & 3;
    float s = 0.f;
    for (int cc = 0; cc < 128; cc++) s += W[(size_t)i * 512 + h * 128 + cc] * A[h * 128 + cc];
    watt[i * 8 + s8] = s;
  }
}

// ---------------- finalize layer2: x = relu(dis*acc+b); att[n][0..7] = x . watt ----------------
__global__ __launch_bounds__(256) void k_fin2(const float* __restrict__ acc,
                                              const float* __restrict__ dis,
                                              const float* __restrict__ b,
                                              const float* __restrict__ watt,
                                              float* __restrict__ att, int M) {
  __shared__ float red[4][8];
  int t = threadIdx.x;
  int rlocal = t >> 7;  // 0..1
  int c = t & 127;
  int row = blockIdx.x * 2 + rlocal;
  float x = 0.f;
  if (row < M) x = fmaxf(dis[row] * acc[(size_t)row * 128 + c] + b[c], 0.f);
  float p[8];
  const float* wp = &watt[c * 8];
#pragma unroll
  for (int h = 0; h < 8; h++) p[h] = x * wp[h];
#pragma unroll
  for (int m = 32; m; m >>= 1) {
#pragma unroll
    for (int h = 0; h < 8; h++) p[h] += __shfl_xor(p[h], m);
  }
  int w = t >> 6;
  if ((t & 63) == 0) {
#pragma unroll
    for (int h = 0; h < 8; h++) red[w][h] = p[h];
  }
  __syncthreads();
  if (t < 16) {
    int rl = t >> 3, h = t & 7;
    int grow = blockIdx.x * 2 + rl;
    if (grow < M) att[(size_t)grow * 8 + h] = red[rl * 2][h] + red[rl * 2 + 1][h];
  }
}

// ---------------- a_src: a_s[n][h] = hs[n,h,:] . att_src[h,:] ----------------
__global__ __launch_bounds__(256) void k_as(const float* __restrict__ hs,
                                            const float* __restrict__ atts,
                                            float* __restrict__ a_s, int N) {
  int t = blockIdx.x * 256 + threadIdx.x;
  if (t >= N * 4) return;
  int n = t >> 2, h = t & 3;
  const float4* hp = (const float4*)&hs[(size_t)n * 512 + h * 128];
  const float4* ap = (const float4*)&atts[h * 128];
  float s = 0.f;
  for (int j = 0; j < 32; j++) {
    float4 a4 = hp[j];
    float4 b4 = ap[j];
    s += a4.x * b4.x + a4.y * b4.y + a4.z * b4.z + a4.w * b4.w;
  }
  a_s[t] = s;
}

// ---------------- GAT edge passes ----------------
// PASS 1: segment max (uint-encoded atomicMax)
// PASS 2: denom += exp(e - m)
// PASS 3: wsrc[src] += alpha
template <int PASS>
__global__ __launch_bounds__(256) void k_edge(const int* __restrict__ src,
                                              const int* __restrict__ dst, int E,
                                              const float* __restrict__ a_s,
                                              const float* __restrict__ att, int attOff,
                                              unsigned* __restrict__ menc,
                                              float* __restrict__ denom,
                                              float* __restrict__ wsrc) {
  int e = blockIdx.x * 256 + threadIdx.x;
  if (e >= E) return;
  int s = src[e], d = dst[e];
  float4 as4 = *(const float4*)&a_s[s * 4];
  float4 ad4 = *(const float4*)&att[(size_t)d * 8 + attOff];
  float v[4] = {as4.x + ad4.x, as4.y + ad4.y, as4.z + ad4.z, as4.w + ad4.w};
#pragma unroll
  for (int h = 0; h < 4; h++) {
    float eh = v[h] > 0.f ? v[h] : 0.2f * v[h];
    if (PASS == 1) {
      atomicMax(&menc[(size_t)d * 4 + h], encf(eh));
    } else if (PASS == 2) {
      float m = decf(menc[(size_t)d * 4 + h]);
      atomAddF(&denom[(size_t)d * 4 + h], __expf(eh - m));
    } else {
      float m = decf(menc[(size_t)d * 4 + h]);
      float al = __expf(eh - m) / (denom[(size_t)d * 4 + h] + 1e-16f);
      atomAddF(&wsrc[(size_t)s * 4 + h], al);
    }
  }
}

// ---------------- weighted column sum: S[h*128+c] += sum_s wsrc[s,h]*hs[s,h,c] ----------------
__global__ __launch_bounds__(512) void k_wsum(const float* __restrict__ hs,
                                              const float* __restrict__ wsrc,
                                              float* __restrict__ S, int N) {
  int t = threadIdx.x;  // 0..511 = h*128+c
  int h = t >> 7;
  int r0 = blockIdx.x * 64;
  int r1 = min(r0 + 64, N);
  float acc = 0.f;
  for (int r = r0; r < r1; r++) acc += wsrc[r * 4 + h] * hs[(size_t)r * 512 + t];
  atomAddF(&S[t], acc);
}

// ---------------- column sum for embedding means ----------------
__global__ __launch_bounds__(128) void k_colsum(const float* __restrict__ x,
                                                float* __restrict__ out, int N) {
  int c = threadIdx.x;
  int r0 = blockIdx.x * 128;
  int r1 = min(r0 + 128, N);
  float acc = 0.f;
  for (int r = r0; r < r1; r++) acc += x[(size_t)r * 128 + c];
  atomAddF(&out[c], acc);
}

// ---------------- final fuse ----------------
__global__ __launch_bounds__(128) void k_final(const float* __restrict__ S_d,
                                               const float* __restrict__ S_c,
                                               const float* __restrict__ bdsum,
                                               const float* __restrict__ bcsum,
                                               const float* __restrict__ bd_bias,
                                               const float* __restrict__ bc_bias,
                                               const float* __restrict__ fuse_w,
                                               const float* __restrict__ fuse_b,
                                               float* __restrict__ out) {
  __shared__ float cat[384];
  int t = threadIdx.x;
  float sd = S_d[t] + S_d[128 + t] + S_d[256 + t] + S_d[384 + t];
  float sc = S_c[t] + S_c[128 + t] + S_c[256 + t] + S_c[384 + t];
  const float inv = 1.0f / (4.0f * (float)NG);
  cat[t] = 0.5f * (sd * inv + bd_bias[t] + sc * inv + bc_bias[t]);
  cat[128 + t] = bdsum[t] * (1.0f / (float)NDR);
  cat[256 + t] = bcsum[t] * (1.0f / (float)NDI);
  __syncthreads();
  float o = fuse_b[t];
  for (int k = 0; k < 384; k++) o += cat[k] * fuse_w[k * 128 + t];
  out[t] = o;
}

// ---------------- host launch ----------------
static inline int cdiv(int a, int b) { return (a + b - 1) / b; }

extern "C" void kernel_launch(void* const* d_in, const int* in_sizes, int n_in,
                              void* d_out, int out_size, void* d_ws, size_t ws_size,
                              hipStream_t stream) {
  const float* gene_nodes   = (const float*)d_in[0];
  const int*   drug_edges   = (const int*)d_in[1];
  const int*   dise_edges   = (const int*)d_in[2];
  const int*   gene_edges   = (const int*)d_in[3];
  const float* gcn1_w       = (const float*)d_in[4];
  const float* gcn1_b       = (const float*)d_in[5];
  const float* gcn2_w       = (const float*)d_in[6];
  const float* gcn2_b       = (const float*)d_in[7];
  const float* drug_embed   = (const float*)d_in[8];
  const float* dise_embed   = (const float*)d_in[9];
  const float* gat_d_w      = (const float*)d_in[10];
  const float* gat_d_att_s  = (const float*)d_in[11];
  const float* gat_d_att_d  = (const float*)d_in[12];
  const float* gat_d_b      = (const float*)d_in[13];
  const float* gat_c_w      = (const float*)d_in[14];
  const float* gat_c_att_s  = (const float*)d_in[15];
  const float* gat_c_att_d  = (const float*)d_in[16];
  const float* gat_c_b      = (const float*)d_in[17];
  const float* fuse_w       = (const float*)d_in[18];
  const float* fuse_b       = (const float*)d_in[19];
  const int Ed = in_sizes[1] / 2;
  const int Ec = in_sizes[2] / 2;
  const int Eg = in_sizes[3] / 2;
  float* out = (float*)d_out;
  (void)n_in; (void)out_size; (void)ws_size;

  // workspace layout (zero-init region first, single memset)
  char* w = (char*)d_ws;
  auto alloc = [&](size_t n) {
    char* p = w;
    w += (n + 511) & ~(size_t)511;
    return p;
  };
  char* z0 = w;
  unsigned* deg     = (unsigned*)alloc((size_t)NG * 4);
  unsigned* menc_d  = (unsigned*)alloc((size_t)NG * 16);
  unsigned* menc_c  = (unsigned*)alloc((size_t)NG * 16);
  float* denom_d    = (float*)alloc((size_t)NG * 16);
  float* denom_c    = (float*)alloc((size_t)NG * 16);
  float* wsrc_d     = (float*)alloc((size_t)NDR * 16);
  float* wsrc_c     = (float*)alloc((size_t)NDI * 16);
  float* S_d        = (float*)alloc(512 * 4);
  float* S_c        = (float*)alloc(512 * 4);
  float* bdsum      = (float*)alloc(512);
  float* bcsum      = (float*)alloc(512);
  size_t zbytes = (size_t)(w - z0);
  float* dis        = (float*)alloc((size_t)NG * 4);
  float* watt       = (float*)alloc(128 * 8 * 4);
  float* att        = (float*)alloc((size_t)NG * 8 * 4);
  float* a_s_d      = (float*)alloc((size_t)NDR * 16);
  float* a_s_c      = (float*)alloc((size_t)NDI * 16);
  float* hh         = (float*)alloc((size_t)NG * 128 * 4);
  float* acc        = (float*)alloc((size_t)NG * 128 * 4);
  float* x1         = (float*)alloc((size_t)NG * 128 * 4);
  // hs buffers alias x1 (x1 is dead after GCN2 GEMM reads it)
  float* hs_d = x1;
  float* hs_c = x1 + (size_t)NDR * 512;

  hipMemsetAsync(z0, 0, zbytes, stream);

  // degree + normalization (shared by both GCN layers)
  k_deg<<<cdiv(Eg, 256), 256, 0, stream>>>(gene_edges + Eg, Eg, deg);
  k_dis<<<cdiv(NG, 256), 256, 0, stream>>>(deg, dis, NG);
  k_watt<<<1, 256, 0, stream>>>(gat_d_w, gat_d_att_d, gat_c_w, gat_c_att_d, watt);

  // GCN layer 1
  k_gemm<0><<<dim3(NG / 32, 1), 256, 0, stream>>>(gene_nodes, gcn1_w, NG, 128, hh, acc, dis);
  k_scatter<<<8192, 256, 0, stream>>>(gene_edges, gene_edges + Eg, Eg, hh, acc);
  k_fin1<<<cdiv(NG * 32, 256), 256, 0, stream>>>(acc, dis, gcn1_b, x1, NG);

  // GCN layer 2 (fused att-score epilogue; x2 never materialized)
  k_gemm<0><<<dim3(NG / 32, 1), 256, 0, stream>>>(x1, gcn2_w, NG, 128, hh, acc, dis);
  k_scatter<<<8192, 256, 0, stream>>>(gene_edges, gene_edges + Eg, Eg, hh, acc);
  k_fin2<<<cdiv(NG, 2), 256, 0, stream>>>(acc, dis, gcn2_b, watt, att, NG);

  // GAT source transforms (hs buffers reuse x1 storage — safe: stream-ordered)
  k_gemm<1><<<dim3(cdiv(NDR, 32), 4), 256, 0, stream>>>(drug_embed, gat_d_w, NDR, 512, hs_d, nullptr, nullptr);
  k_gemm<1><<<dim3(cdiv(NDI, 32), 4), 256, 0, stream>>>(dise_embed, gat_c_w, NDI, 512, hs_c, nullptr, nullptr);
  k_as<<<cdiv(NDR * 4, 256), 256, 0, stream>>>(hs_d, gat_d_att_s, a_s_d, NDR);
  k_as<<<cdiv(NDI * 4, 256), 256, 0, stream>>>(hs_c, gat_c_att_s, a_s_c, NDI);

  // GAT softmax edge passes (drug->gene uses att slots 0..3, disease->gene 4..7)
  k_edge<1><<<cdiv(Ed, 256), 256, 0, stream>>>(drug_edges, drug_edges + Ed, Ed, a_s_d, att, 0, menc_d, denom_d, wsrc_d);
  k_edge<2><<<cdiv(Ed, 256), 256, 0, stream>>>(drug_edges, drug_edges + Ed, Ed, a_s_d, att, 0, menc_d, denom_d, wsrc_d);
  k_edge<3><<<cdiv(Ed, 256), 256, 0, stream>>>(drug_edges, drug_edges + Ed, Ed, a_s_d, att, 0, menc_d, denom_d, wsrc_d);
  k_edge<1><<<cdiv(Ec, 256), 256, 0, stream>>>(dise_edges, dise_edges + Ec, Ec, a_s_c, att, 4, menc_c, denom_c, wsrc_c);
  k_edge<2><<<cdiv(Ec, 256), 256, 0, stream>>>(dise_edges, dise_edges + Ec, Ec, a_s_c, att, 4, menc_c, denom_c, wsrc_c);
  k_edge<3><<<cdiv(Ec, 256), 256, 0, stream>>>(dise_edges, dise_edges + Ec, Ec, a_s_c, att, 4, menc_c, denom_c, wsrc_c);

  // weighted column sums (replaces the 100K-node GAT output scatter entirely)
  k_wsum<<<cdiv(NDR, 64), 512, 0, stream>>>(hs_d, wsrc_d, S_d, NDR);
  k_wsum<<<cdiv(NDI, 64), 512, 0, stream>>>(hs_c, wsrc_c, S_c, NDI);
  k_colsum<<<cdiv(NDR, 128), 128, 0, stream>>>(drug_embed, bdsum, NDR);
  k_colsum<<<cdiv(NDI, 128), 128, 0, stream>>>(dise_embed, bcsum, NDI);

  // final fuse
  k_final<<<1, 128, 0, stream>>>(S_d, S_c, bdsum, bcsum, gat_d_b, gat_c_b, fuse_w, fuse_b, out);
}

// Round 2
// 1018.081 us; speedup vs baseline: 4.1819x; 4.1819x over previous
//
#include <hip/hip_runtime.h>

#define NG 100000
#define NDR 10000
#define NDI 5000

__device__ __forceinline__ void atomAddF(float* p, float v) { unsafeAtomicAdd(p, v); }

__device__ __forceinline__ unsigned encf(float f) {
  unsigned u = __float_as_uint(f);
  return (u & 0x80000000u) ? ~u : (u | 0x80000000u);
}
__device__ __forceinline__ float decf(unsigned u) {
  return __uint_as_float((u & 0x80000000u) ? (u ^ 0x80000000u) : ~u);
}

// ---------------- degree / normalization ----------------
__global__ __launch_bounds__(256) void k_deg(const int* __restrict__ dst, int E,
                                             unsigned* __restrict__ deg) {
  int e = blockIdx.x * 256 + threadIdx.x;
  if (e < E) atomicAdd(&deg[dst[e]], 1u);
}

__global__ __launch_bounds__(256) void k_dis(const unsigned* __restrict__ deg,
                                             float* __restrict__ dis, int n) {
  int i = blockIdx.x * 256 + threadIdx.x;
  if (i < n) dis[i] = rsqrtf((float)deg[i] + 1.0f);
}

// ---------------- CSR build: blocksum -> scan partials -> rowptr -> fill ----------------
__global__ __launch_bounds__(256) void k_blocksum(const unsigned* __restrict__ deg,
                                                  unsigned* __restrict__ partial, int n) {
  __shared__ unsigned s[256];
  int t = threadIdx.x;
  int i = blockIdx.x * 256 + t;
  s[t] = (i < n) ? deg[i] : 0u;
  __syncthreads();
  for (int off = 128; off; off >>= 1) {
    if (t < off) s[t] += s[t + off];
    __syncthreads();
  }
  if (!t) partial[blockIdx.x] = s[0];
}

__global__ __launch_bounds__(512) void k_scanpart(unsigned* __restrict__ partial, int nb) {
  __shared__ unsigned s[512];
  int t = threadIdx.x;
  unsigned v = (t < nb) ? partial[t] : 0u;
  s[t] = v;
  __syncthreads();
  for (int off = 1; off < 512; off <<= 1) {
    unsigned add = (t >= off) ? s[t - off] : 0u;
    __syncthreads();
    s[t] += add;
    __syncthreads();
  }
  if (t < nb) partial[t] = s[t] - v;  // exclusive
}

__global__ __launch_bounds__(256) void k_rowptr(const unsigned* __restrict__ deg,
                                                const unsigned* __restrict__ partial, int n,
                                                int* __restrict__ rowptr,
                                                int* __restrict__ cursor) {
  __shared__ unsigned s[256];
  int t = threadIdx.x;
  int i = blockIdx.x * 256 + t;
  unsigned v = (i < n) ? deg[i] : 0u;
  s[t] = v;
  __syncthreads();
  for (int off = 1; off < 256; off <<= 1) {
    unsigned add = (t >= off) ? s[t - off] : 0u;
    __syncthreads();
    s[t] += add;
    __syncthreads();
  }
  unsigned excl = s[t] - v + partial[blockIdx.x];
  if (i <= n) {
    rowptr[i] = (int)excl;
    if (i < n) cursor[i] = (int)excl;
  }
}

__global__ __launch_bounds__(256) void k_fill(const int* __restrict__ src,
                                              const int* __restrict__ dst, int E,
                                              int* __restrict__ cursor,
                                              int* __restrict__ adj) {
  int e = blockIdx.x * 256 + threadIdx.x;
  if (e < E) {
    int d = dst[e];
    int p = atomicAdd(&cursor[d], 1);
    adj[p] = src[e];
  }
}

// ---------------- GEMM: X[M,128] @ W[128,N], col tile 128 ----------------
// MODE 0: v = dot * dis[row] -> out   (GCN, pre-scaled by src norm)
// MODE 1: v = dot -> out              (GAT hs)
template <int MODE>
__global__ __launch_bounds__(256) void k_gemm(const float* __restrict__ X,
                                              const float* __restrict__ W, int M, int N,
                                              float* __restrict__ out,
                                              const float* __restrict__ dis) {
  __shared__ float Ws[128][128];
  __shared__ float Xs[32][128];
  const int t = threadIdx.x;
  const int row0 = blockIdx.x * 32;
  const int col0 = blockIdx.y * 128;

  for (int i = t; i < 128 * 32; i += 256) {
    int k = i >> 5;
    int c4 = (i & 31) << 2;
    *(float4*)&Ws[k][c4] = *(const float4*)&W[(size_t)k * N + col0 + c4];
  }
  for (int i = t; i < 32 * 32; i += 256) {
    int r = i >> 5;
    int c4 = (i & 31) << 2;
    int gr = row0 + r;
    float4 v = make_float4(0.f, 0.f, 0.f, 0.f);
    if (gr < M) v = *(const float4*)&X[(size_t)gr * 128 + c4];
    *(float4*)&Xs[r][c4] = v;
  }
  __syncthreads();

  const int tc = (t & 15) * 8;
  const int tr = (t >> 4) * 2;
  float a[2][8];
#pragma unroll
  for (int r = 0; r < 2; r++)
#pragma unroll
    for (int j = 0; j < 8; j++) a[r][j] = 0.f;

  for (int k = 0; k < 128; k += 4) {
    float4 xa = *(const float4*)&Xs[tr][k];
    float4 xb = *(const float4*)&Xs[tr + 1][k];
    const float* xap = (const float*)&xa;
    const float* xbp = (const float*)&xb;
#pragma unroll
    for (int kk = 0; kk < 4; kk++) {
      float4 w0 = *(const float4*)&Ws[k + kk][tc];
      float4 w1 = *(const float4*)&Ws[k + kk][tc + 4];
      float x0 = xap[kk];
      float x1v = xbp[kk];
      a[0][0] += x0 * w0.x; a[0][1] += x0 * w0.y; a[0][2] += x0 * w0.z; a[0][3] += x0 * w0.w;
      a[0][4] += x0 * w1.x; a[0][5] += x0 * w1.y; a[0][6] += x0 * w1.z; a[0][7] += x0 * w1.w;
      a[1][0] += x1v * w0.x; a[1][1] += x1v * w0.y; a[1][2] += x1v * w0.z; a[1][3] += x1v * w0.w;
      a[1][4] += x1v * w1.x; a[1][5] += x1v * w1.y; a[1][6] += x1v * w1.z; a[1][7] += x1v * w1.w;
    }
  }

#pragma unroll
  for (int rr = 0; rr < 2; rr++) {
    int g = row0 + tr + rr;
    if (g < M) {
      float scale = (MODE == 0) ? dis[g] : 1.0f;
      float4 v0 = make_float4(a[rr][0] * scale, a[rr][1] * scale, a[rr][2] * scale, a[rr][3] * scale);
      float4 v1 = make_float4(a[rr][4] * scale, a[rr][5] * scale, a[rr][6] * scale, a[rr][7] * scale);
      size_t base = (size_t)g * N + col0 + tc;
      *(float4*)&out[base] = v0;
      *(float4*)&out[base + 4] = v1;
    }
  }
}

// ---------------- GCN aggregation by CSR gather, wave per dst node ----------------
// FIN 1: out = x1 row = relu(dis*sum + b)                       [NG,128]
// FIN 2: out = att row (8 scores) = relu-row . watt             [NG,8]
template <int FIN>
__global__ __launch_bounds__(256) void k_gather(const float* __restrict__ hh,
                                                const int* __restrict__ rowptr,
                                                const int* __restrict__ adj,
                                                const float* __restrict__ dis,
                                                const float* __restrict__ b,
                                                const float* __restrict__ watt,
                                                float* __restrict__ out, int n) {
  int wid = threadIdx.x >> 6;
  int lane = threadIdx.x & 63;
  int d = blockIdx.x * 4 + wid;
  if (d >= n) return;
  int p0 = rowptr[d], p1 = rowptr[d + 1];
  int c = lane * 2;
  float2 s = *(const float2*)&hh[(size_t)d * 128 + c];  // self loop
  for (int base = p0; base < p1; base += 64) {
    int remain = p1 - base;
    int idx = (lane < remain) ? adj[base + lane] : 0;
    int m = remain < 64 ? remain : 64;
    for (int j = 0; j < m; j++) {
      int nb = __shfl(idx, j);
      float2 v = *(const float2*)&hh[(size_t)nb * 128 + c];
      s.x += v.x;
      s.y += v.y;
    }
  }
  float dd = dis[d];
  float x0 = fmaxf(dd * s.x + b[c], 0.f);
  float x1v = fmaxf(dd * s.y + b[c + 1], 0.f);
  if (FIN == 1) {
    *(float2*)&out[(size_t)d * 128 + c] = make_float2(x0, x1v);
  } else {
    float p[8];
    const float* w0 = &watt[c * 8];
#pragma unroll
    for (int h = 0; h < 8; h++) p[h] = x0 * w0[h] + x1v * w0[8 + h];
#pragma unroll
    for (int mm = 32; mm; mm >>= 1) {
#pragma unroll
      for (int h = 0; h < 8; h++) p[h] += __shfl_xor(p[h], mm);
    }
    if (lane == 0) {
#pragma unroll
      for (int h = 0; h < 8; h++) out[(size_t)d * 8 + h] = p[h];
    }
  }
}

// ---------------- make w_att: watt[c][slot] slot 0..3 drug, 4..7 disease ----------------
__global__ __launch_bounds__(256) void k_watt(const float* __restrict__ wd,
                                              const float* __restrict__ attd_d,
                                              const float* __restrict__ wc,
                                              const float* __restrict__ attd_c,
                                              float* __restrict__ watt) {
  int t = threadIdx.x;
  for (int slot = t; slot < 1024; slot += 256) {
    int i = slot >> 3, s8 = slot & 7;
    const float* W = (s8 < 4) ? wd : wc;
    const float* A = (s8 < 4) ? attd_d : attd_c;
    int h = s8 & 3;
    float s = 0.f;
    for (int cc = 0; cc < 128; cc++) s += W[(size_t)i * 512 + h * 128 + cc] * A[h * 128 + cc];
    watt[i * 8 + s8] = s;
  }
}

// ---------------- a_src: a_s[n][h] = hs[n,h,:] . att_src[h,:] ----------------
__global__ __launch_bounds__(256) void k_as(const float* __restrict__ hs,
                                            const float* __restrict__ atts,
                                            float* __restrict__ a_s, int N) {
  int t = blockIdx.x * 256 + threadIdx.x;
  if (t >= N * 4) return;
  int n = t >> 2, h = t & 3;
  const float4* hp = (const float4*)&hs[(size_t)n * 512 + h * 128];
  const float4* ap = (const float4*)&atts[h * 128];
  float s = 0.f;
  for (int j = 0; j < 32; j++) {
    float4 a4 = hp[j];
    float4 b4 = ap[j];
    s += a4.x * b4.x + a4.y * b4.y + a4.z * b4.z + a4.w * b4.w;
  }
  a_s[t] = s;
}

// ---------------- GAT edge passes ----------------
template <int PASS>
__global__ __launch_bounds__(256) void k_edge(const int* __restrict__ src,
                                              const int* __restrict__ dst, int E,
                                              const float* __restrict__ a_s,
                                              const float* __restrict__ att, int attOff,
                                              unsigned* __restrict__ menc,
                                              float* __restrict__ denom,
                                              float* __restrict__ wsrc) {
  int e = blockIdx.x * 256 + threadIdx.x;
  if (e >= E) return;
  int s = src[e], d = dst[e];
  float4 as4 = *(const float4*)&a_s[s * 4];
  float4 ad4 = *(const float4*)&att[(size_t)d * 8 + attOff];
  float v[4] = {as4.x + ad4.x, as4.y + ad4.y, as4.z + ad4.z, as4.w + ad4.w};
#pragma unroll
  for (int h = 0; h < 4; h++) {
    float eh = v[h] > 0.f ? v[h] : 0.2f * v[h];
    if (PASS == 1) {
      atomicMax(&menc[(size_t)d * 4 + h], encf(eh));
    } else if (PASS == 2) {
      float m = decf(menc[(size_t)d * 4 + h]);
      atomAddF(&denom[(size_t)d * 4 + h], __expf(eh - m));
    } else {
      float m = decf(menc[(size_t)d * 4 + h]);
      float al = __expf(eh - m) / (denom[(size_t)d * 4 + h] + 1e-16f);
      atomAddF(&wsrc[(size_t)s * 4 + h], al);
    }
  }
}

// ---------------- weighted column sum: S[h*128+c] += sum_s wsrc[s,h]*hs[s,h,c] ----------------
__global__ __launch_bounds__(512) void k_wsum(const float* __restrict__ hs,
                                              const float* __restrict__ wsrc,
                                              float* __restrict__ S, int N) {
  int t = threadIdx.x;  // 0..511 = h*128+c
  int h = t >> 7;
  int r0 = blockIdx.x * 64;
  int r1 = min(r0 + 64, N);
  float acc = 0.f;
  for (int r = r0; r < r1; r++) acc += wsrc[r * 4 + h] * hs[(size_t)r * 512 + t];
  atomAddF(&S[t], acc);
}

// ---------------- column sum for embedding means ----------------
__global__ __launch_bounds__(128) void k_colsum(const float* __restrict__ x,
                                                float* __restrict__ out, int N) {
  int c = threadIdx.x;
  int r0 = blockIdx.x * 128;
  int r1 = min(r0 + 128, N);
  float acc = 0.f;
  for (int r = r0; r < r1; r++) acc += x[(size_t)r * 128 + c];
  atomAddF(&out[c], acc);
}

// ---------------- final fuse ----------------
__global__ __launch_bounds__(128) void k_final(const float* __restrict__ S_d,
                                               const float* __restrict__ S_c,
                                               const float* __restrict__ bdsum,
                                               const float* __restrict__ bcsum,
                                               const float* __restrict__ bd_bias,
                                               const float* __restrict__ bc_bias,
                                               const float* __restrict__ fuse_w,
                                               const float* __restrict__ fuse_b,
                                               float* __restrict__ out) {
  __shared__ float cat[384];
  int t = threadIdx.x;
  float sd = S_d[t] + S_d[128 + t] + S_d[256 + t] + S_d[384 + t];
  float sc = S_c[t] + S_c[128 + t] + S_c[256 + t] + S_c[384 + t];
  const float inv = 1.0f / (4.0f * (float)NG);
  cat[t] = 0.5f * (sd * inv + bd_bias[t] + sc * inv + bc_bias[t]);
  cat[128 + t] = bdsum[t] * (1.0f / (float)NDR);
  cat[256 + t] = bcsum[t] * (1.0f / (float)NDI);
  __syncthreads();
  float o = fuse_b[t];
  for (int k = 0; k < 384; k++) o += cat[k] * fuse_w[k * 128 + t];
  out[t] = o;
}

// ---------------- host launch ----------------
static inline int cdiv(int a, int b) { return (a + b - 1) / b; }

extern "C" void kernel_launch(void* const* d_in, const int* in_sizes, int n_in,
                              void* d_out, int out_size, void* d_ws, size_t ws_size,
                              hipStream_t stream) {
  const float* gene_nodes   = (const float*)d_in[0];
  const int*   drug_edges   = (const int*)d_in[1];
  const int*   dise_edges   = (const int*)d_in[2];
  const int*   gene_edges   = (const int*)d_in[3];
  const float* gcn1_w       = (const float*)d_in[4];
  const float* gcn1_b       = (const float*)d_in[5];
  const float* gcn2_w       = (const float*)d_in[6];
  const float* gcn2_b       = (const float*)d_in[7];
  const float* drug_embed   = (const float*)d_in[8];
  const float* dise_embed   = (const float*)d_in[9];
  const float* gat_d_w      = (const float*)d_in[10];
  const float* gat_d_att_s  = (const float*)d_in[11];
  const float* gat_d_att_d  = (const float*)d_in[12];
  const float* gat_d_b      = (const float*)d_in[13];
  const float* gat_c_w      = (const float*)d_in[14];
  const float* gat_c_att_s  = (const float*)d_in[15];
  const float* gat_c_att_d  = (const float*)d_in[16];
  const float* gat_c_b      = (const float*)d_in[17];
  const float* fuse_w       = (const float*)d_in[18];
  const float* fuse_b       = (const float*)d_in[19];
  const int Ed = in_sizes[1] / 2;
  const int Ec = in_sizes[2] / 2;
  const int Eg = in_sizes[3] / 2;
  float* out = (float*)d_out;
  (void)n_in; (void)out_size; (void)ws_size;

  const int NBLK = cdiv(NG, 256);  // 391 scan blocks

  // workspace layout (zero-init region first, single memset)
  char* w = (char*)d_ws;
  auto alloc = [&](size_t n) {
    char* p = w;
    w += (n + 511) & ~(size_t)511;
    return p;
  };
  char* z0 = w;
  unsigned* deg     = (unsigned*)alloc((size_t)NG * 4);
  unsigned* menc_d  = (unsigned*)alloc((size_t)NG * 16);
  unsigned* menc_c  = (unsigned*)alloc((size_t)NG * 16);
  float* denom_d    = (float*)alloc((size_t)NG * 16);
  float* denom_c    = (float*)alloc((size_t)NG * 16);
  float* wsrc_d     = (float*)alloc((size_t)NDR * 16);
  float* wsrc_c     = (float*)alloc((size_t)NDI * 16);
  float* S_d        = (float*)alloc(512 * 4);
  float* S_c        = (float*)alloc(512 * 4);
  float* bdsum      = (float*)alloc(512);
  float* bcsum      = (float*)alloc(512);
  size_t zbytes = (size_t)(w - z0);
  float* dis        = (float*)alloc((size_t)NG * 4);
  float* watt       = (float*)alloc(128 * 8 * 4);
  float* att        = (float*)alloc((size_t)NG * 8 * 4);
  float* a_s_d      = (float*)alloc((size_t)NDR * 16);
  float* a_s_c      = (float*)alloc((size_t)NDI * 16);
  unsigned* partial = (unsigned*)alloc((size_t)512 * 4);
  int* rowptr       = (int*)alloc((size_t)(NG + 1) * 4);
  int* cursor       = (int*)alloc((size_t)NG * 4);
  int* adj          = (int*)alloc((size_t)Eg * 4);
  float* hh         = (float*)alloc((size_t)NG * 128 * 4);
  float* x1         = (float*)alloc((size_t)NG * 128 * 4);
  // hs buffers alias x1 (x1 is dead after GCN2 GEMM reads it)
  float* hs_d = x1;
  float* hs_c = x1 + (size_t)NDR * 512;

  hipMemsetAsync(z0, 0, zbytes, stream);

  // degree + normalization + CSR (shared by both GCN layers)
  k_deg<<<cdiv(Eg, 256), 256, 0, stream>>>(gene_edges + Eg, Eg, deg);
  k_dis<<<cdiv(NG, 256), 256, 0, stream>>>(deg, dis, NG);
  k_blocksum<<<NBLK, 256, 0, stream>>>(deg, partial, NG);
  k_scanpart<<<1, 512, 0, stream>>>(partial, NBLK);
  k_rowptr<<<NBLK, 256, 0, stream>>>(deg, partial, NG, rowptr, cursor);
  k_fill<<<cdiv(Eg, 256), 256, 0, stream>>>(gene_edges, gene_edges + Eg, Eg, cursor, adj);
  k_watt<<<1, 256, 0, stream>>>(gat_d_w, gat_d_att_d, gat_c_w, gat_c_att_d, watt);

  // GCN layer 1: GEMM -> gather(+relu+bias)
  k_gemm<0><<<dim3(cdiv(NG, 32), 1), 256, 0, stream>>>(gene_nodes, gcn1_w, NG, 128, hh, dis);
  k_gather<1><<<cdiv(NG, 4), 256, 0, stream>>>(hh, rowptr, adj, dis, gcn1_b, nullptr, x1, NG);

  // GCN layer 2: GEMM -> gather(+relu+bias+att-score epilogue); x2 never materialized
  k_gemm<0><<<dim3(cdiv(NG, 32), 1), 256, 0, stream>>>(x1, gcn2_w, NG, 128, hh, dis);
  k_gather<2><<<cdiv(NG, 4), 256, 0, stream>>>(hh, rowptr, adj, dis, gcn2_b, watt, att, NG);

  // GAT source transforms (hs buffers reuse x1 storage — safe: stream-ordered)
  k_gemm<1><<<dim3(cdiv(NDR, 32), 4), 256, 0, stream>>>(drug_embed, gat_d_w, NDR, 512, hs_d, nullptr);
  k_gemm<1><<<dim3(cdiv(NDI, 32), 4), 256, 0, stream>>>(dise_embed, gat_c_w, NDI, 512, hs_c, nullptr);
  k_as<<<cdiv(NDR * 4, 256), 256, 0, stream>>>(hs_d, gat_d_att_s, a_s_d, NDR);
  k_as<<<cdiv(NDI * 4, 256), 256, 0, stream>>>(hs_c, gat_c_att_s, a_s_c, NDI);

  // GAT softmax edge passes (drug->gene uses att slots 0..3, disease->gene 4..7)
  k_edge<1><<<cdiv(Ed, 256), 256, 0, stream>>>(drug_edges, drug_edges + Ed, Ed, a_s_d, att, 0, menc_d, denom_d, wsrc_d);
  k_edge<2><<<cdiv(Ed, 256), 256, 0, stream>>>(drug_edges, drug_edges + Ed, Ed, a_s_d, att, 0, menc_d, denom_d, wsrc_d);
  k_edge<3><<<cdiv(Ed, 256), 256, 0, stream>>>(drug_edges, drug_edges + Ed, Ed, a_s_d, att, 0, menc_d, denom_d, wsrc_d);
  k_edge<1><<<cdiv(Ec, 256), 256, 0, stream>>>(dise_edges, dise_edges + Ec, Ec, a_s_c, att, 4, menc_c, denom_c, wsrc_c);
  k_edge<2><<<cdiv(Ec, 256), 256, 0, stream>>>(dise_edges, dise_edges + Ec, Ec, a_s_c, att, 4, menc_c, denom_c, wsrc_c);
  k_edge<3><<<cdiv(Ec, 256), 256, 0, stream>>>(dise_edges, dise_edges + Ec, Ec, a_s_c, att, 4, menc_c, denom_c, wsrc_c);

  // weighted column sums (replaces the 100K-node GAT output scatter entirely)
  k_wsum<<<cdiv(NDR, 64), 512, 0, stream>>>(hs_d, wsrc_d, S_d, NDR);
  k_wsum<<<cdiv(NDI, 64), 512, 0, stream>>>(hs_c, wsrc_c, S_c, NDI);
  k_colsum<<<cdiv(NDR, 128), 128, 0, stream>>>(drug_embed, bdsum, NDR);
  k_colsum<<<cdiv(NDI, 128), 128, 0, stream>>>(dise_embed, bcsum, NDI);

  // final fuse
  k_final<<<1, 128, 0, stream>>>(S_d, S_c, bdsum, bcsum, gat_d_b, gat_c_b, fuse_w, fuse_b, out);
}

// Round 3
// 849.085 us; speedup vs baseline: 5.0143x; 1.1990x over previous
//
#include <hip/hip_runtime.h>
#include <hip/hip_fp16.h>

#define NG 100000
#define NDR 10000
#define NDI 5000

__device__ __forceinline__ void atomAddF(float* p, float v) { unsafeAtomicAdd(p, v); }

// ---------------- degree ----------------
__global__ __launch_bounds__(256) void k_deg(const int* __restrict__ dst, int E,
                                             unsigned* __restrict__ deg) {
  int e = blockIdx.x * 256 + threadIdx.x;
  if (e < E) atomicAdd(&deg[dst[e]], 1u);
}

// ---------------- CSR build: blocksum -> scan partials -> rowptr(+dis) -> fill ----------------
__global__ __launch_bounds__(256) void k_blocksum(const unsigned* __restrict__ deg,
                                                  unsigned* __restrict__ partial, int n) {
  __shared__ unsigned s[256];
  int t = threadIdx.x;
  int i = blockIdx.x * 256 + t;
  s[t] = (i < n) ? deg[i] : 0u;
  __syncthreads();
  for (int off = 128; off; off >>= 1) {
    if (t < off) s[t] += s[t + off];
    __syncthreads();
  }
  if (!t) partial[blockIdx.x] = s[0];
}

__global__ __launch_bounds__(512) void k_scanpart(unsigned* __restrict__ partial, int nb) {
  __shared__ unsigned s[512];
  int t = threadIdx.x;
  unsigned v = (t < nb) ? partial[t] : 0u;
  s[t] = v;
  __syncthreads();
  for (int off = 1; off < 512; off <<= 1) {
    unsigned add = (t >= off) ? s[t - off] : 0u;
    __syncthreads();
    s[t] += add;
    __syncthreads();
  }
  if (t < nb) partial[t] = s[t] - v;  // exclusive
}

__global__ __launch_bounds__(256) void k_rowptr(const unsigned* __restrict__ deg,
                                                const unsigned* __restrict__ partial, int n,
                                                int* __restrict__ rowptr,
                                                int* __restrict__ cursor,
                                                float* __restrict__ dis) {
  __shared__ unsigned s[256];
  int t = threadIdx.x;
  int i = blockIdx.x * 256 + t;
  unsigned v = (i < n) ? deg[i] : 0u;
  s[t] = v;
  __syncthreads();
  for (int off = 1; off < 256; off <<= 1) {
    unsigned add = (t >= off) ? s[t - off] : 0u;
    __syncthreads();
    s[t] += add;
    __syncthreads();
  }
  unsigned excl = s[t] - v + partial[blockIdx.x];
  if (i <= n) {
    rowptr[i] = (int)excl;
    if (i < n) {
      cursor[i] = (int)excl;
      dis[i] = rsqrtf((float)v + 1.0f);
    }
  }
}

__global__ __launch_bounds__(256) void k_fill(const int* __restrict__ src,
                                              const int* __restrict__ dst, int E,
                                              int* __restrict__ cursor,
                                              int* __restrict__ adj) {
  int e = blockIdx.x * 256 + threadIdx.x;
  if (e < E) {
    int d = dst[e];
    int p = atomicAdd(&cursor[d], 1);
    adj[p] = src[e];
  }
}

// ---------------- GEMM: X[M,128] @ W[128,N], col tile 128, conflict-free LDS ----------------
// Per-thread: 4 rows x 4 contiguous cols. c4=(t&31)*4 (stride-float4, conflict-free),
// r0=(t>>5)*4 (near-broadcast X reads).
// MODE 0: out __half = dot * dis[row]              (GCN hh, fp16)
// MODE 1: out float = dot; fused a_s epilogue      (GAT hs; blockIdx.y = head)
template <int MODE, typename OutT>
__global__ __launch_bounds__(256) void k_gemm(const float* __restrict__ X,
                                              const float* __restrict__ W, int M, int N,
                                              OutT* __restrict__ out,
                                              const float* __restrict__ dis,
                                              const float* __restrict__ atts,
                                              float* __restrict__ a_s) {
  __shared__ float Ws[128][128];
  __shared__ float Xs[32][128];
  const int t = threadIdx.x;
  const int row0 = blockIdx.x * 32;
  const int col0 = blockIdx.y * 128;

  for (int i = t; i < 128 * 32; i += 256) {
    int k = i >> 5;
    int c = (i & 31) << 2;
    *(float4*)&Ws[k][c] = *(const float4*)&W[(size_t)k * N + col0 + c];
  }
  for (int i = t; i < 32 * 32; i += 256) {
    int r = i >> 5;
    int c = (i & 31) << 2;
    int gr = row0 + r;
    float4 v = make_float4(0.f, 0.f, 0.f, 0.f);
    if (gr < M) v = *(const float4*)&X[(size_t)gr * 128 + c];
    *(float4*)&Xs[r][c] = v;
  }
  __syncthreads();

  const int c4 = (t & 31) * 4;
  const int r0 = (t >> 5) * 4;
  float acc[4][4];
#pragma unroll
  for (int r = 0; r < 4; r++)
#pragma unroll
    for (int j = 0; j < 4; j++) acc[r][j] = 0.f;

  for (int k = 0; k < 128; k += 4) {
    float4 wv[4];
#pragma unroll
    for (int kk = 0; kk < 4; kk++) wv[kk] = *(const float4*)&Ws[k + kk][c4];
#pragma unroll
    for (int r = 0; r < 4; r++) {
      float4 xv = *(const float4*)&Xs[r0 + r][k];
      const float* xp = (const float*)&xv;
#pragma unroll
      for (int kk = 0; kk < 4; kk++) {
        float x = xp[kk];
        acc[r][0] += x * wv[kk].x;
        acc[r][1] += x * wv[kk].y;
        acc[r][2] += x * wv[kk].z;
        acc[r][3] += x * wv[kk].w;
      }
    }
  }

  if (MODE == 0) {
#pragma unroll
    for (int r = 0; r < 4; r++) {
      int g = row0 + r0 + r;
      if (g < M) {
        float sc = dis[g];
        __half2 h01 = __floats2half2_rn(acc[r][0] * sc, acc[r][1] * sc);
        __half2 h23 = __floats2half2_rn(acc[r][2] * sc, acc[r][3] * sc);
        uint2 pk;
        pk.x = *(unsigned*)&h01;
        pk.y = *(unsigned*)&h23;
        *(uint2*)&((__half*)out)[(size_t)g * N + col0 + c4] = pk;
      }
    }
  } else {
    const int h = blockIdx.y;
    float4 av = *(const float4*)&atts[h * 128 + c4];
    float p[4];
#pragma unroll
    for (int r = 0; r < 4; r++) {
      int g = row0 + r0 + r;
      if (g < M) {
        *(float4*)&((float*)out)[(size_t)g * N + col0 + c4] =
            make_float4(acc[r][0], acc[r][1], acc[r][2], acc[r][3]);
      }
      p[r] = acc[r][0] * av.x + acc[r][1] * av.y + acc[r][2] * av.z + acc[r][3] * av.w;
    }
#pragma unroll
    for (int m = 1; m < 32; m <<= 1) {
#pragma unroll
      for (int r = 0; r < 4; r++) p[r] += __shfl_xor(p[r], m);
    }
    if ((t & 31) == 0) {
#pragma unroll
      for (int r = 0; r < 4; r++) {
        int g = row0 + r0 + r;
        if (g < M) a_s[(size_t)g * 4 + h] = p[r];
      }
    }
  }
}

// ---------------- GCN aggregation by CSR gather (fp16 hh), wave per dst node ----------------
// FIN 1: out = x1 row = relu(dis*sum + b)                       [NG,128] fp32
// FIN 2: out = att row (8 scores) = relu-row . watt             [NG,8]
template <int FIN>
__global__ __launch_bounds__(256) void k_gather(const __half2* __restrict__ hh2,
                                                const int* __restrict__ rowptr,
                                                const int* __restrict__ adj,
                                                const float* __restrict__ dis,
                                                const float* __restrict__ b,
                                                const float* __restrict__ watt,
                                                float* __restrict__ out, int n) {
  int wid = threadIdx.x >> 6;
  int lane = threadIdx.x & 63;
  int d = blockIdx.x * 4 + wid;
  if (d >= n) return;
  int p0 = rowptr[d], p1 = rowptr[d + 1];
  int c = lane * 2;
  float2 s = __half22float2(hh2[(size_t)d * 64 + lane]);  // self loop
  for (int base = p0; base < p1; base += 64) {
    int remain = p1 - base;
    int idx = (lane < remain) ? adj[base + lane] : 0;
    int m = remain < 64 ? remain : 64;
    for (int j = 0; j < m; j++) {
      int nb = __shfl(idx, j);
      float2 v = __half22float2(hh2[(size_t)nb * 64 + lane]);
      s.x += v.x;
      s.y += v.y;
    }
  }
  float dd = dis[d];
  float x0 = fmaxf(dd * s.x + b[c], 0.f);
  float x1v = fmaxf(dd * s.y + b[c + 1], 0.f);
  if (FIN == 1) {
    *(float2*)&out[(size_t)d * 128 + c] = make_float2(x0, x1v);
  } else {
    float p[8];
    const float* w0 = &watt[c * 8];
#pragma unroll
    for (int h = 0; h < 8; h++) p[h] = x0 * w0[h] + x1v * w0[8 + h];
#pragma unroll
    for (int mm = 32; mm; mm >>= 1) {
#pragma unroll
      for (int h = 0; h < 8; h++) p[h] += __shfl_xor(p[h], mm);
    }
    if (lane == 0) {
#pragma unroll
      for (int h = 0; h < 8; h++) out[(size_t)d * 8 + h] = p[h];
    }
  }
}

// ---------------- make w_att: watt[c][slot] slot 0..3 drug, 4..7 disease ----------------
__global__ __launch_bounds__(256) void k_watt(const float* __restrict__ wd,
                                              const float* __restrict__ attd_d,
                                              const float* __restrict__ wc,
                                              const float* __restrict__ attd_c,
                                              float* __restrict__ watt) {
  int t = threadIdx.x;
  for (int slot = t; slot < 1024; slot += 256) {
    int i = slot >> 3, s8 = slot & 7;
    const float* W = (s8 < 4) ? wd : wc;
    const float* A = (s8 < 4) ? attd_d : attd_c;
    int h = s8 & 3;
    float s = 0.f;
    for (int cc = 0; cc < 128; cc++) s += W[(size_t)i * 512 + h * 128 + cc] * A[h * 128 + cc];
    watt[i * 8 + s8] = s;
  }
}

// ---------------- GAT edge passes (no max pass: scores ~N(0,1), exp safe) ----------------
// PASS 2: denom[d] += exp(e)
// PASS 3: wsrc[s]  += exp(e)/denom[d]
template <int PASS>
__global__ __launch_bounds__(256) void k_edge(const int* __restrict__ src,
                                              const int* __restrict__ dst, int E,
                                              const float* __restrict__ a_s,
                                              const float* __restrict__ att, int attOff,
                                              float* __restrict__ denom,
                                              float* __restrict__ wsrc) {
  int e = blockIdx.x * 256 + threadIdx.x;
  if (e >= E) return;
  int s = src[e], d = dst[e];
  float4 as4 = *(const float4*)&a_s[s * 4];
  float4 ad4 = *(const float4*)&att[(size_t)d * 8 + attOff];
  float v[4] = {as4.x + ad4.x, as4.y + ad4.y, as4.z + ad4.z, as4.w + ad4.w};
#pragma unroll
  for (int h = 0; h < 4; h++) {
    float eh = v[h] > 0.f ? v[h] : 0.2f * v[h];
    eh = fminf(eh, 50.f);
    if (PASS == 2) {
      atomAddF(&denom[(size_t)d * 4 + h], __expf(eh));
    } else {
      float al = __expf(eh) / (denom[(size_t)d * 4 + h] + 1e-16f);
      atomAddF(&wsrc[(size_t)s * 4 + h], al);
    }
  }
}

// ---------------- weighted column sum: S[h*128+c] += sum_s wsrc[s,h]*hs[s,h,c] ----------------
__global__ __launch_bounds__(512) void k_wsum(const float* __restrict__ hs,
                                              const float* __restrict__ wsrc,
                                              float* __restrict__ S, int N) {
  int t = threadIdx.x;  // 0..511 = h*128+c
  int h = t >> 7;
  int r0 = blockIdx.x * 64;
  int r1 = min(r0 + 64, N);
  float acc = 0.f;
  for (int r = r0; r < r1; r++) acc += wsrc[r * 4 + h] * hs[(size_t)r * 512 + t];
  atomAddF(&S[t], acc);
}

// ---------------- column sum for embedding means ----------------
__global__ __launch_bounds__(128) void k_colsum(const float* __restrict__ x,
                                                float* __restrict__ out, int N) {
  int c = threadIdx.x;
  int r0 = blockIdx.x * 128;
  int r1 = min(r0 + 128, N);
  float acc = 0.f;
  for (int r = r0; r < r1; r++) acc += x[(size_t)r * 128 + c];
  atomAddF(&out[c], acc);
}

// ---------------- final fuse ----------------
__global__ __launch_bounds__(128) void k_final(const float* __restrict__ S_d,
                                               const float* __restrict__ S_c,
                                               const float* __restrict__ bdsum,
                                               const float* __restrict__ bcsum,
                                               const float* __restrict__ bd_bias,
                                               const float* __restrict__ bc_bias,
                                               const float* __restrict__ fuse_w,
                                               const float* __restrict__ fuse_b,
                                               float* __restrict__ out) {
  __shared__ float cat[384];
  int t = threadIdx.x;
  float sd = S_d[t] + S_d[128 + t] + S_d[256 + t] + S_d[384 + t];
  float sc = S_c[t] + S_c[128 + t] + S_c[256 + t] + S_c[384 + t];
  const float inv = 1.0f / (4.0f * (float)NG);
  cat[t] = 0.5f * (sd * inv + bd_bias[t] + sc * inv + bc_bias[t]);
  cat[128 + t] = bdsum[t] * (1.0f / (float)NDR);
  cat[256 + t] = bcsum[t] * (1.0f / (float)NDI);
  __syncthreads();
  float o = fuse_b[t];
  for (int k = 0; k < 384; k++) o += cat[k] * fuse_w[k * 128 + t];
  out[t] = o;
}

// ---------------- host launch ----------------
static inline int cdiv(int a, int b) { return (a + b - 1) / b; }

extern "C" void kernel_launch(void* const* d_in, const int* in_sizes, int n_in,
                              void* d_out, int out_size, void* d_ws, size_t ws_size,
                              hipStream_t stream) {
  const float* gene_nodes   = (const float*)d_in[0];
  const int*   drug_edges   = (const int*)d_in[1];
  const int*   dise_edges   = (const int*)d_in[2];
  const int*   gene_edges   = (const int*)d_in[3];
  const float* gcn1_w       = (const float*)d_in[4];
  const float* gcn1_b       = (const float*)d_in[5];
  const float* gcn2_w       = (const float*)d_in[6];
  const float* gcn2_b       = (const float*)d_in[7];
  const float* drug_embed   = (const float*)d_in[8];
  const float* dise_embed   = (const float*)d_in[9];
  const float* gat_d_w      = (const float*)d_in[10];
  const float* gat_d_att_s  = (const float*)d_in[11];
  const float* gat_d_att_d  = (const float*)d_in[12];
  const float* gat_d_b      = (const float*)d_in[13];
  const float* gat_c_w      = (const float*)d_in[14];
  const float* gat_c_att_s  = (const float*)d_in[15];
  const float* gat_c_att_d  = (const float*)d_in[16];
  const float* gat_c_b      = (const float*)d_in[17];
  const float* fuse_w       = (const float*)d_in[18];
  const float* fuse_b       = (const float*)d_in[19];
  const int Ed = in_sizes[1] / 2;
  const int Ec = in_sizes[2] / 2;
  const int Eg = in_sizes[3] / 2;
  float* out = (float*)d_out;
  (void)n_in; (void)out_size; (void)ws_size;

  const int NBLK = cdiv(NG, 256);  // 391 scan blocks

  // workspace layout (zero-init region first, single memset)
  char* w = (char*)d_ws;
  auto alloc = [&](size_t n) {
    char* p = w;
    w += (n + 511) & ~(size_t)511;
    return p;
  };
  char* z0 = w;
  unsigned* deg     = (unsigned*)alloc((size_t)NG * 4);
  float* denom_d    = (float*)alloc((size_t)NG * 16);
  float* denom_c    = (float*)alloc((size_t)NG * 16);
  float* wsrc_d     = (float*)alloc((size_t)NDR * 16);
  float* wsrc_c     = (float*)alloc((size_t)NDI * 16);
  float* S_d        = (float*)alloc(512 * 4);
  float* S_c        = (float*)alloc(512 * 4);
  float* bdsum      = (float*)alloc(512);
  float* bcsum      = (float*)alloc(512);
  size_t zbytes = (size_t)(w - z0);
  float* dis        = (float*)alloc((size_t)NG * 4);
  float* watt       = (float*)alloc(128 * 8 * 4);
  float* att        = (float*)alloc((size_t)NG * 8 * 4);
  float* a_s_d      = (float*)alloc((size_t)NDR * 16);
  float* a_s_c      = (float*)alloc((size_t)NDI * 16);
  unsigned* partial = (unsigned*)alloc((size_t)512 * 4);
  int* rowptr       = (int*)alloc((size_t)(NG + 1) * 4);
  int* cursor       = (int*)alloc((size_t)NG * 4);
  int* adj          = (int*)alloc((size_t)Eg * 4);
  __half* hh        = (__half*)alloc((size_t)NG * 128 * 2);
  float* x1         = (float*)alloc((size_t)NG * 128 * 4);
  // hs buffers alias x1 (x1 is dead after GCN2 GEMM reads it)
  float* hs_d = x1;
  float* hs_c = x1 + (size_t)NDR * 512;

  hipMemsetAsync(z0, 0, zbytes, stream);

  // degree + normalization + CSR (shared by both GCN layers)
  k_deg<<<cdiv(Eg, 256), 256, 0, stream>>>(gene_edges + Eg, Eg, deg);
  k_blocksum<<<NBLK, 256, 0, stream>>>(deg, partial, NG);
  k_scanpart<<<1, 512, 0, stream>>>(partial, NBLK);
  k_rowptr<<<NBLK, 256, 0, stream>>>(deg, partial, NG, rowptr, cursor, dis);
  k_fill<<<cdiv(Eg, 256), 256, 0, stream>>>(gene_edges, gene_edges + Eg, Eg, cursor, adj);
  k_watt<<<1, 256, 0, stream>>>(gat_d_w, gat_d_att_d, gat_c_w, gat_c_att_d, watt);

  // GCN layer 1: GEMM (fp16 out) -> gather(+relu+bias)
  k_gemm<0, __half><<<dim3(cdiv(NG, 32), 1), 256, 0, stream>>>(gene_nodes, gcn1_w, NG, 128, hh, dis, nullptr, nullptr);
  k_gather<1><<<cdiv(NG, 4), 256, 0, stream>>>((const __half2*)hh, rowptr, adj, dis, gcn1_b, nullptr, x1, NG);

  // GCN layer 2: GEMM -> gather(+relu+bias+att-score epilogue); x2 never materialized
  k_gemm<0, __half><<<dim3(cdiv(NG, 32), 1), 256, 0, stream>>>(x1, gcn2_w, NG, 128, hh, dis, nullptr, nullptr);
  k_gather<2><<<cdiv(NG, 4), 256, 0, stream>>>((const __half2*)hh, rowptr, adj, dis, gcn2_b, watt, att, NG);

  // GAT source transforms with fused a_s epilogue (hs aliases x1 — stream-ordered)
  k_gemm<1, float><<<dim3(cdiv(NDR, 32), 4), 256, 0, stream>>>(drug_embed, gat_d_w, NDR, 512, hs_d, nullptr, gat_d_att_s, a_s_d);
  k_gemm<1, float><<<dim3(cdiv(NDI, 32), 4), 256, 0, stream>>>(dise_embed, gat_c_w, NDI, 512, hs_c, nullptr, gat_c_att_s, a_s_c);

  // GAT softmax edge passes (no max pass; drug uses att slots 0..3, disease 4..7)
  k_edge<2><<<cdiv(Ed, 256), 256, 0, stream>>>(drug_edges, drug_edges + Ed, Ed, a_s_d, att, 0, denom_d, wsrc_d);
  k_edge<3><<<cdiv(Ed, 256), 256, 0, stream>>>(drug_edges, drug_edges + Ed, Ed, a_s_d, att, 0, denom_d, wsrc_d);
  k_edge<2><<<cdiv(Ec, 256), 256, 0, stream>>>(dise_edges, dise_edges + Ec, Ec, a_s_c, att, 4, denom_c, wsrc_c);
  k_edge<3><<<cdiv(Ec, 256), 256, 0, stream>>>(dise_edges, dise_edges + Ec, Ec, a_s_c, att, 4, denom_c, wsrc_c);

  // weighted column sums (replaces the 100K-node GAT output scatter entirely)
  k_wsum<<<cdiv(NDR, 64), 512, 0, stream>>>(hs_d, wsrc_d, S_d, NDR);
  k_wsum<<<cdiv(NDI, 64), 512, 0, stream>>>(hs_c, wsrc_c, S_c, NDI);
  k_colsum<<<cdiv(NDR, 128), 128, 0, stream>>>(drug_embed, bdsum, NDR);
  k_colsum<<<cdiv(NDI, 128), 128, 0, stream>>>(dise_embed, bcsum, NDI);

  // final fuse
  k_final<<<1, 128, 0, stream>>>(S_d, S_c, bdsum, bcsum, gat_d_b, gat_c_b, fuse_w, fuse_b, out);
}

// Round 4
// 809.666 us; speedup vs baseline: 5.2584x; 1.0487x over previous
//
#include <hip/hip_runtime.h>
#include <hip/hip_fp16.h>

#define NG 100000
#define NDR 10000
#define NDI 5000

typedef _Float16 f16x8 __attribute__((ext_vector_type(8)));
typedef float f32x4 __attribute__((ext_vector_type(4)));

__device__ __forceinline__ void atomAddF(float* p, float v) { unsafeAtomicAdd(p, v); }

// ---------------- degree ----------------
__global__ __launch_bounds__(256) void k_deg(const int* __restrict__ dst, int E,
                                             unsigned* __restrict__ deg) {
  int e = blockIdx.x * 256 + threadIdx.x;
  if (e < E) atomicAdd(&deg[dst[e]], 1u);
}

// ---------------- CSR build: blocksum -> scan partials -> rowptr(+dis) -> fill ----------------
__global__ __launch_bounds__(256) void k_blocksum(const unsigned* __restrict__ deg,
                                                  unsigned* __restrict__ partial, int n) {
  __shared__ unsigned s[256];
  int t = threadIdx.x;
  int i = blockIdx.x * 256 + t;
  s[t] = (i < n) ? deg[i] : 0u;
  __syncthreads();
  for (int off = 128; off; off >>= 1) {
    if (t < off) s[t] += s[t + off];
    __syncthreads();
  }
  if (!t) partial[blockIdx.x] = s[0];
}

__global__ __launch_bounds__(512) void k_scanpart(unsigned* __restrict__ partial, int nb) {
  __shared__ unsigned s[512];
  int t = threadIdx.x;
  unsigned v = (t < nb) ? partial[t] : 0u;
  s[t] = v;
  __syncthreads();
  for (int off = 1; off < 512; off <<= 1) {
    unsigned add = (t >= off) ? s[t - off] : 0u;
    __syncthreads();
    s[t] += add;
    __syncthreads();
  }
  if (t < nb) partial[t] = s[t] - v;  // exclusive
}

__global__ __launch_bounds__(256) void k_rowptr(const unsigned* __restrict__ deg,
                                                const unsigned* __restrict__ partial, int n,
                                                int* __restrict__ rowptr,
                                                int* __restrict__ cursor,
                                                float* __restrict__ dis) {
  __shared__ unsigned s[256];
  int t = threadIdx.x;
  int i = blockIdx.x * 256 + t;
  unsigned v = (i < n) ? deg[i] : 0u;
  s[t] = v;
  __syncthreads();
  for (int off = 1; off < 256; off <<= 1) {
    unsigned add = (t >= off) ? s[t - off] : 0u;
    __syncthreads();
    s[t] += add;
    __syncthreads();
  }
  unsigned excl = s[t] - v + partial[blockIdx.x];
  if (i <= n) {
    rowptr[i] = (int)excl;
    if (i < n) {
      cursor[i] = (int)excl;
      dis[i] = rsqrtf((float)v + 1.0f);
    }
  }
}

__global__ __launch_bounds__(256) void k_fill(const int* __restrict__ src,
                                              const int* __restrict__ dst, int E,
                                              int* __restrict__ cursor,
                                              int* __restrict__ adj) {
  int e = blockIdx.x * 256 + threadIdx.x;
  if (e < E) {
    int d = dst[e];
    int p = atomicAdd(&cursor[d], 1);
    adj[p] = src[e];
  }
}

// ---------------- W prep: Wt[n][k] f16 from W[k][n] f32, both GCN weights ----------------
__global__ __launch_bounds__(256) void k_wprep(const float* __restrict__ W1,
                                               const float* __restrict__ W2,
                                               __half* __restrict__ Wt1,
                                               __half* __restrict__ Wt2) {
  const float* W = blockIdx.x ? W2 : W1;
  __half* Wt = blockIdx.x ? Wt2 : Wt1;
  for (int q = threadIdx.x; q < 16384; q += 256) {
    int n = q >> 7, k = q & 127;
    Wt[q] = __float2half(W[k * 128 + n]);
  }
}

// ---------------- MFMA f16 GEMM: hh[M,128] = (X[M,128] @ W) * dis[row], f16 out ----------------
// LDS XOR-swizzle (byte ^= (row&7)<<4) on both tiles; Wt pre-transposed [n][k].
__global__ __launch_bounds__(256) void k_mgemm(const float* __restrict__ X,
                                               const __half* __restrict__ Wt, int M,
                                               const float* __restrict__ dis,
                                               __half* __restrict__ hh) {
  __shared__ __align__(16) char lds[48 * 1024];
  char* As = lds;              // 64 x 128 f16 = 16 KB
  char* Bs = lds + 16 * 1024;  // 128 x 128 f16 = 32 KB
  const int t = threadIdx.x;
  const int row0 = blockIdx.x * 64;

  // stage Wt -> Bs (swizzled)
#pragma unroll
  for (int rep = 0; rep < 16; rep++) {
    int q = t + rep * 256;               // uint2 index (4 halfs), 4096 total
    int r = q >> 5, c8 = (q & 31) * 8;   // byte col
    uint2 v = *(const uint2*)((const char*)Wt + r * 256 + c8);
    *(uint2*)(Bs + ((r * 256 + c8) ^ ((r & 7) << 4))) = v;
  }
  // stage X -> As (f32 -> f16, swizzled)
#pragma unroll
  for (int rep = 0; rep < 8; rep++) {
    int q = t + rep * 256;               // float4 index, 2048 total
    int r = q >> 5, c4 = (q & 31) * 4;   // f32 col
    int gr = row0 + r;
    float4 xv = make_float4(0.f, 0.f, 0.f, 0.f);
    if (gr < M) xv = *(const float4*)&X[(size_t)gr * 128 + c4];
    __half2 h0 = __floats2half2_rn(xv.x, xv.y);
    __half2 h1 = __floats2half2_rn(xv.z, xv.w);
    uint2 pk;
    pk.x = *(unsigned*)&h0;
    pk.y = *(unsigned*)&h1;
    *(uint2*)(As + ((r * 256 + c4 * 2) ^ ((r & 7) << 4))) = pk;
  }
  __syncthreads();

  const int w = t >> 6, l = t & 63;
  const int lr = l & 15, lk = l >> 4;  // lr: row/col in tile, lk: k-group 0..3
  f32x4 acc[8] = {};
#pragma unroll
  for (int s = 0; s < 4; s++) {  // K step of 32
    int arow = w * 16 + lr;
    f16x8 a = *(const f16x8*)(As + ((arow * 256 + lk * 16 + s * 64) ^ ((arow & 7) << 4)));
#pragma unroll
    for (int nt = 0; nt < 8; nt++) {
      int brow = nt * 16 + lr;
      f16x8 b = *(const f16x8*)(Bs + ((brow * 256 + lk * 16 + s * 64) ^ ((brow & 7) << 4)));
      acc[nt] = __builtin_amdgcn_mfma_f32_16x16x32_f16(a, b, acc[nt], 0, 0, 0);
    }
  }
  // epilogue: D row=(lk*4+j), col=lr within tile
  float ddv[4];
  int rowb = row0 + w * 16 + lk * 4;
#pragma unroll
  for (int j = 0; j < 4; j++) ddv[j] = (rowb + j < M) ? dis[rowb + j] : 0.f;
#pragma unroll
  for (int nt = 0; nt < 8; nt++) {
#pragma unroll
    for (int j = 0; j < 4; j++) {
      int row = rowb + j;
      if (row < M) hh[(size_t)row * 128 + nt * 16 + lr] = __float2half(acc[nt][j] * ddv[j]);
    }
  }
}

// ---------------- GCN aggregation: CSR gather, wave/dst, 4x16 groups, loads in flight ----------------
// FIN 1: out = x1 row = relu(dis*sum + b)                 [NG,128] fp32
// FIN 2: out = att row (8 scores) = relu-row . watt       [NG,8]
template <int FIN>
__global__ __launch_bounds__(256) void k_gather(const __half* __restrict__ hh,
                                                const int* __restrict__ rowptr,
                                                const int* __restrict__ adj,
                                                const float* __restrict__ dis,
                                                const float* __restrict__ b,
                                                const float* __restrict__ watt,
                                                float* __restrict__ out, int n) {
  int wid = threadIdx.x >> 6;
  int lane = threadIdx.x & 63;
  int g = lane >> 4, sl = lane & 15;
  int d = blockIdx.x * 4 + wid;
  if (d >= n) return;
  int p0 = rowptr[d], p1 = rowptr[d + 1];
  float acc[8] = {0.f, 0.f, 0.f, 0.f, 0.f, 0.f, 0.f, 0.f};

  // self loop (group 0 carries it)
  {
    uint4 rv = *(const uint4*)&hh[(size_t)d * 128 + sl * 8];
    float wg = (g == 0) ? 1.f : 0.f;
    const __half2* hp = (const __half2*)&rv;
#pragma unroll
    for (int q = 0; q < 4; q++) {
      float2 f = __half22float2(hp[q]);
      acc[2 * q] += wg * f.x;
      acc[2 * q + 1] += wg * f.y;
    }
  }
  for (int b0 = p0; b0 < p1; b0 += 64) {
    int remain = p1 - b0;
    int idx = (lane < remain) ? adj[b0 + lane] : 0;
    int m = remain < 64 ? remain : 64;
    for (int j0 = 0; j0 < m; j0 += 16) {
#pragma unroll
      for (int u = 0; u < 4; u++) {
        int j = j0 + u * 4 + g;  // <= 63 always
        int nb = __shfl(idx, j);
        float wg = (j < m) ? 1.f : 0.f;
        uint4 rv = *(const uint4*)&hh[(size_t)nb * 128 + sl * 8];
        const __half2* hp = (const __half2*)&rv;
#pragma unroll
        for (int q = 0; q < 4; q++) {
          float2 f = __half22float2(hp[q]);
          acc[2 * q] += wg * f.x;
          acc[2 * q + 1] += wg * f.y;
        }
      }
    }
  }
  // reduce across the 4 groups
#pragma unroll
  for (int i = 0; i < 8; i++) {
    acc[i] += __shfl_xor(acc[i], 16);
    acc[i] += __shfl_xor(acc[i], 32);
  }
  float dd = dis[d];
  float x[8];
#pragma unroll
  for (int i = 0; i < 8; i++) x[i] = fmaxf(dd * acc[i] + b[sl * 8 + i], 0.f);

  if (FIN == 1) {
    if (g == 0) {
      float4 v0 = make_float4(x[0], x[1], x[2], x[3]);
      float4 v1 = make_float4(x[4], x[5], x[6], x[7]);
      *(float4*)&out[(size_t)d * 128 + sl * 8] = v0;
      *(float4*)&out[(size_t)d * 128 + sl * 8 + 4] = v1;
    }
  } else {
    float p[8] = {0.f, 0.f, 0.f, 0.f, 0.f, 0.f, 0.f, 0.f};
#pragma unroll
    for (int i = 0; i < 8; i++) {
      const float* wp = &watt[(sl * 8 + i) * 8];
#pragma unroll
      for (int h = 0; h < 8; h++) p[h] += x[i] * wp[h];
    }
#pragma unroll
    for (int mm = 1; mm < 16; mm <<= 1) {
#pragma unroll
      for (int h = 0; h < 8; h++) p[h] += __shfl_xor(p[h], mm);
    }
    if (lane == 0) {
      *(float4*)&out[(size_t)d * 8] = make_float4(p[0], p[1], p[2], p[3]);
      *(float4*)&out[(size_t)d * 8 + 4] = make_float4(p[4], p[5], p[6], p[7]);
    }
  }
}

// ---------------- fp32 GEMM for GAT hs: X[M,128]@W[128,512] + fused a_s epilogue ----------------
__global__ __launch_bounds__(256) void k_gemm(const float* __restrict__ X,
                                              const float* __restrict__ W, int M, int N,
                                              float* __restrict__ out,
                                              const float* __restrict__ atts,
                                              float* __restrict__ a_s) {
  __shared__ float Ws[128][128];
  __shared__ float Xs[32][128];
  const int t = threadIdx.x;
  const int row0 = blockIdx.x * 32;
  const int col0 = blockIdx.y * 128;

  for (int i = t; i < 128 * 32; i += 256) {
    int k = i >> 5;
    int c = (i & 31) << 2;
    *(float4*)&Ws[k][c] = *(const float4*)&W[(size_t)k * N + col0 + c];
  }
  for (int i = t; i < 32 * 32; i += 256) {
    int r = i >> 5;
    int c = (i & 31) << 2;
    int gr = row0 + r;
    float4 v = make_float4(0.f, 0.f, 0.f, 0.f);
    if (gr < M) v = *(const float4*)&X[(size_t)gr * 128 + c];
    *(float4*)&Xs[r][c] = v;
  }
  __syncthreads();

  const int c4 = (t & 31) * 4;
  const int r0 = (t >> 5) * 4;
  float acc[4][4];
#pragma unroll
  for (int r = 0; r < 4; r++)
#pragma unroll
    for (int j = 0; j < 4; j++) acc[r][j] = 0.f;

  for (int k = 0; k < 128; k += 4) {
    float4 wv[4];
#pragma unroll
    for (int kk = 0; kk < 4; kk++) wv[kk] = *(const float4*)&Ws[k + kk][c4];
#pragma unroll
    for (int r = 0; r < 4; r++) {
      float4 xv = *(const float4*)&Xs[r0 + r][k];
      const float* xp = (const float*)&xv;
#pragma unroll
      for (int kk = 0; kk < 4; kk++) {
        float x = xp[kk];
        acc[r][0] += x * wv[kk].x;
        acc[r][1] += x * wv[kk].y;
        acc[r][2] += x * wv[kk].z;
        acc[r][3] += x * wv[kk].w;
      }
    }
  }

  const int h = blockIdx.y;
  float4 av = *(const float4*)&atts[h * 128 + c4];
  float p[4];
#pragma unroll
  for (int r = 0; r < 4; r++) {
    int g = row0 + r0 + r;
    if (g < M) {
      *(float4*)&out[(size_t)g * N + col0 + c4] =
          make_float4(acc[r][0], acc[r][1], acc[r][2], acc[r][3]);
    }
    p[r] = acc[r][0] * av.x + acc[r][1] * av.y + acc[r][2] * av.z + acc[r][3] * av.w;
  }
#pragma unroll
  for (int m = 1; m < 32; m <<= 1) {
#pragma unroll
    for (int r = 0; r < 4; r++) p[r] += __shfl_xor(p[r], m);
  }
  if ((t & 31) == 0) {
#pragma unroll
    for (int r = 0; r < 4; r++) {
      int g = row0 + r0 + r;
      if (g < M) a_s[(size_t)g * 4 + h] = p[r];
    }
  }
}

// ---------------- make w_att: watt[c][slot] slot 0..3 drug, 4..7 disease ----------------
__global__ __launch_bounds__(256) void k_watt(const float* __restrict__ wd,
                                              const float* __restrict__ attd_d,
                                              const float* __restrict__ wc,
                                              const float* __restrict__ attd_c,
                                              float* __restrict__ watt) {
  int t = threadIdx.x;
  for (int slot = t; slot < 1024; slot += 256) {
    int i = slot >> 3, s8 = slot & 7;
    const float* W = (s8 < 4) ? wd : wc;
    const float* A = (s8 < 4) ? attd_d : attd_c;
    int h = s8 & 3;
    float s = 0.f;
    for (int cc = 0; cc < 128; cc++) s += W[(size_t)i * 512 + h * 128 + cc] * A[h * 128 + cc];
    watt[i * 8 + s8] = s;
  }
}

// ---------------- GAT edge passes, both graphs in one launch ----------------
// PASS 2: denom[d] += exp(e);  PASS 3: wsrc[s] += exp(e)/denom[d]
template <int PASS>
__global__ __launch_bounds__(256) void k_edge(const int* __restrict__ ed, int Ed_,
                                              const float* __restrict__ asd,
                                              float* __restrict__ dend,
                                              float* __restrict__ wsd,
                                              const int* __restrict__ ec, int Ec_,
                                              const float* __restrict__ asc,
                                              float* __restrict__ denc,
                                              float* __restrict__ wsc,
                                              const float* __restrict__ att) {
  int nbd = (Ed_ + 255) >> 8;
  int blk = blockIdx.x;
  const int* src;
  const int* dst;
  const float* a_s;
  float* den;
  float* ws;
  int E, attOff, e;
  if (blk < nbd) {
    src = ed; dst = ed + Ed_; a_s = asd; den = dend; ws = wsd; E = Ed_; attOff = 0;
    e = blk * 256 + threadIdx.x;
  } else {
    src = ec; dst = ec + Ec_; a_s = asc; den = denc; ws = wsc; E = Ec_; attOff = 4;
    e = (blk - nbd) * 256 + threadIdx.x;
  }
  if (e >= E) return;
  int s = src[e], d = dst[e];
  float4 as4 = *(const float4*)&a_s[s * 4];
  float4 ad4 = *(const float4*)&att[(size_t)d * 8 + attOff];
  float v[4] = {as4.x + ad4.x, as4.y + ad4.y, as4.z + ad4.z, as4.w + ad4.w};
#pragma unroll
  for (int h = 0; h < 4; h++) {
    float eh = v[h] > 0.f ? v[h] : 0.2f * v[h];
    eh = fminf(eh, 50.f);
    if (PASS == 2) {
      atomAddF(&den[(size_t)d * 4 + h], __expf(eh));
    } else {
      float al = __expf(eh) / (den[(size_t)d * 4 + h] + 1e-16f);
      atomAddF(&ws[(size_t)s * 4 + h], al);
    }
  }
}

// ---------------- weighted column sums, both graphs in one launch ----------------
__global__ __launch_bounds__(512) void k_wsum(const float* __restrict__ hs_d,
                                              const float* __restrict__ wsrc_d,
                                              float* __restrict__ S_d, int Nd,
                                              const float* __restrict__ hs_c,
                                              const float* __restrict__ wsrc_c,
                                              float* __restrict__ S_c, int Nc) {
  int nbd = (Nd + 63) >> 6;
  int blk = blockIdx.x;
  const float *hs, *wsrc;
  float* S;
  int r0, N;
  if (blk < nbd) { hs = hs_d; wsrc = wsrc_d; S = S_d; N = Nd; r0 = blk * 64; }
  else { hs = hs_c; wsrc = wsrc_c; S = S_c; N = Nc; r0 = (blk - nbd) * 64; }
  int t = threadIdx.x;  // 0..511 = h*128+c
  int h = t >> 7;
  int r1 = min(r0 + 64, N);
  float acc = 0.f;
  for (int r = r0; r < r1; r++) acc += wsrc[r * 4 + h] * hs[(size_t)r * 512 + t];
  atomAddF(&S[t], acc);
}

__global__ __launch_bounds__(128) void k_colsum(const float* __restrict__ xd,
                                                float* __restrict__ od, int Nd,
                                                const float* __restrict__ xc,
                                                float* __restrict__ oc, int Nc) {
  int nbd = (Nd + 127) >> 7;
  int blk = blockIdx.x;
  const float* x;
  float* o;
  int r0, N;
  if (blk < nbd) { x = xd; o = od; N = Nd; r0 = blk * 128; }
  else { x = xc; o = oc; N = Nc; r0 = (blk - nbd) * 128; }
  int c = threadIdx.x;
  int r1 = min(r0 + 128, N);
  float acc = 0.f;
  for (int r = r0; r < r1; r++) acc += x[(size_t)r * 128 + c];
  atomAddF(&o[c], acc);
}

// ---------------- final fuse ----------------
__global__ __launch_bounds__(128) void k_final(const float* __restrict__ S_d,
                                               const float* __restrict__ S_c,
                                               const float* __restrict__ bdsum,
                                               const float* __restrict__ bcsum,
                                               const float* __restrict__ bd_bias,
                                               const float* __restrict__ bc_bias,
                                               const float* __restrict__ fuse_w,
                                               const float* __restrict__ fuse_b,
                                               float* __restrict__ out) {
  __shared__ float cat[384];
  int t = threadIdx.x;
  float sd = S_d[t] + S_d[128 + t] + S_d[256 + t] + S_d[384 + t];
  float sc = S_c[t] + S_c[128 + t] + S_c[256 + t] + S_c[384 + t];
  const float inv = 1.0f / (4.0f * (float)NG);
  cat[t] = 0.5f * (sd * inv + bd_bias[t] + sc * inv + bc_bias[t]);
  cat[128 + t] = bdsum[t] * (1.0f / (float)NDR);
  cat[256 + t] = bcsum[t] * (1.0f / (float)NDI);
  __syncthreads();
  float o = fuse_b[t];
  for (int k = 0; k < 384; k++) o += cat[k] * fuse_w[k * 128 + t];
  out[t] = o;
}

// ---------------- host launch ----------------
static inline int cdiv(int a, int b) { return (a + b - 1) / b; }

extern "C" void kernel_launch(void* const* d_in, const int* in_sizes, int n_in,
                              void* d_out, int out_size, void* d_ws, size_t ws_size,
                              hipStream_t stream) {
  const float* gene_nodes   = (const float*)d_in[0];
  const int*   drug_edges   = (const int*)d_in[1];
  const int*   dise_edges   = (const int*)d_in[2];
  const int*   gene_edges   = (const int*)d_in[3];
  const float* gcn1_w       = (const float*)d_in[4];
  const float* gcn1_b       = (const float*)d_in[5];
  const float* gcn2_w       = (const float*)d_in[6];
  const float* gcn2_b       = (const float*)d_in[7];
  const float* drug_embed   = (const float*)d_in[8];
  const float* dise_embed   = (const float*)d_in[9];
  const float* gat_d_w      = (const float*)d_in[10];
  const float* gat_d_att_s  = (const float*)d_in[11];
  const float* gat_d_att_d  = (const float*)d_in[12];
  const float* gat_d_b      = (const float*)d_in[13];
  const float* gat_c_w      = (const float*)d_in[14];
  const float* gat_c_att_s  = (const float*)d_in[15];
  const float* gat_c_att_d  = (const float*)d_in[16];
  const float* gat_c_b      = (const float*)d_in[17];
  const float* fuse_w       = (const float*)d_in[18];
  const float* fuse_b       = (const float*)d_in[19];
  const int Ed = in_sizes[1] / 2;
  const int Ec = in_sizes[2] / 2;
  const int Eg = in_sizes[3] / 2;
  float* out = (float*)d_out;
  (void)n_in; (void)out_size; (void)ws_size;

  const int NBLK = cdiv(NG, 256);  // 391 scan blocks

  // workspace layout (zero-init region first, single memset)
  char* w = (char*)d_ws;
  auto alloc = [&](size_t n) {
    char* p = w;
    w += (n + 511) & ~(size_t)511;
    return p;
  };
  char* z0 = w;
  unsigned* deg     = (unsigned*)alloc((size_t)NG * 4);
  float* denom_d    = (float*)alloc((size_t)NG * 16);
  float* denom_c    = (float*)alloc((size_t)NG * 16);
  float* wsrc_d     = (float*)alloc((size_t)NDR * 16);
  float* wsrc_c     = (float*)alloc((size_t)NDI * 16);
  float* S_d        = (float*)alloc(512 * 4);
  float* S_c        = (float*)alloc(512 * 4);
  float* bdsum      = (float*)alloc(512);
  float* bcsum      = (float*)alloc(512);
  size_t zbytes = (size_t)(w - z0);
  float* dis        = (float*)alloc((size_t)NG * 4);
  float* watt       = (float*)alloc(128 * 8 * 4);
  float* att        = (float*)alloc((size_t)NG * 8 * 4);
  float* a_s_d      = (float*)alloc((size_t)NDR * 16);
  float* a_s_c      = (float*)alloc((size_t)NDI * 16);
  unsigned* partial = (unsigned*)alloc((size_t)512 * 4);
  int* rowptr       = (int*)alloc((size_t)(NG + 1) * 4);
  int* cursor       = (int*)alloc((size_t)NG * 4);
  int* adj          = (int*)alloc((size_t)Eg * 4);
  __half* Wt1       = (__half*)alloc((size_t)128 * 128 * 2);
  __half* Wt2       = (__half*)alloc((size_t)128 * 128 * 2);
  __half* hh        = (__half*)alloc((size_t)NG * 128 * 2);
  float* x1         = (float*)alloc((size_t)NG * 128 * 4);
  // hs buffers alias x1 (x1 is dead after GCN2 GEMM reads it)
  float* hs_d = x1;
  float* hs_c = x1 + (size_t)NDR * 512;

  hipMemsetAsync(z0, 0, zbytes, stream);

  // degree + normalization + CSR (shared by both GCN layers) + weight prep
  k_deg<<<cdiv(Eg, 256), 256, 0, stream>>>(gene_edges + Eg, Eg, deg);
  k_blocksum<<<NBLK, 256, 0, stream>>>(deg, partial, NG);
  k_scanpart<<<1, 512, 0, stream>>>(partial, NBLK);
  k_rowptr<<<NBLK, 256, 0, stream>>>(deg, partial, NG, rowptr, cursor, dis);
  k_fill<<<cdiv(Eg, 256), 256, 0, stream>>>(gene_edges, gene_edges + Eg, Eg, cursor, adj);
  k_wprep<<<2, 256, 0, stream>>>(gcn1_w, gcn2_w, Wt1, Wt2);
  k_watt<<<1, 256, 0, stream>>>(gat_d_w, gat_d_att_d, gat_c_w, gat_c_att_d, watt);

  // GCN layer 1: MFMA GEMM (f16 out, pre-scaled by dis[src]) -> gather(+relu+bias)
  k_mgemm<<<cdiv(NG, 64), 256, 0, stream>>>(gene_nodes, Wt1, NG, dis, hh);
  k_gather<1><<<cdiv(NG, 4), 256, 0, stream>>>(hh, rowptr, adj, dis, gcn1_b, nullptr, x1, NG);

  // GCN layer 2: MFMA GEMM -> gather(+relu+bias+att-score epilogue); x2 never materialized
  k_mgemm<<<cdiv(NG, 64), 256, 0, stream>>>(x1, Wt2, NG, dis, hh);
  k_gather<2><<<cdiv(NG, 4), 256, 0, stream>>>(hh, rowptr, adj, dis, gcn2_b, watt, att, NG);

  // GAT source transforms with fused a_s epilogue (hs aliases x1 — stream-ordered)
  k_gemm<<<dim3(cdiv(NDR, 32), 4), 256, 0, stream>>>(drug_embed, gat_d_w, NDR, 512, hs_d, gat_d_att_s, a_s_d);
  k_gemm<<<dim3(cdiv(NDI, 32), 4), 256, 0, stream>>>(dise_embed, gat_c_w, NDI, 512, hs_c, gat_c_att_s, a_s_c);

  // GAT softmax edge passes (both graphs per launch)
  int nbe = cdiv(Ed, 256) + cdiv(Ec, 256);
  k_edge<2><<<nbe, 256, 0, stream>>>(drug_edges, Ed, a_s_d, denom_d, wsrc_d,
                                     dise_edges, Ec, a_s_c, denom_c, wsrc_c, att);
  k_edge<3><<<nbe, 256, 0, stream>>>(drug_edges, Ed, a_s_d, denom_d, wsrc_d,
                                     dise_edges, Ec, a_s_c, denom_c, wsrc_c, att);

  // weighted column sums + embedding means
  k_wsum<<<cdiv(NDR, 64) + cdiv(NDI, 64), 512, 0, stream>>>(hs_d, wsrc_d, S_d, NDR,
                                                            hs_c, wsrc_c, S_c, NDI);
  k_colsum<<<cdiv(NDR, 128) + cdiv(NDI, 128), 128, 0, stream>>>(drug_embed, bdsum, NDR,
                                                                dise_embed, bcsum, NDI);

  // final fuse
  k_final<<<1, 128, 0, stream>>>(S_d, S_c, bdsum, bcsum, gat_d_b, gat_c_b, fuse_w, fuse_b, out);
}

// Round 5
// 686.658 us; speedup vs baseline: 6.2004x; 1.1791x over previous
//
#include <hip/hip_runtime.h>
#include <hip/hip_fp16.h>

#define NG 100000
#define NDR 10000
#define NDI 5000

typedef _Float16 f16x8 __attribute__((ext_vector_type(8)));
typedef float f32x4 __attribute__((ext_vector_type(4)));

__device__ __forceinline__ void atomAddF(float* p, float v) { unsafeAtomicAdd(p, v); }

// ---------------- degree ----------------
__global__ __launch_bounds__(256) void k_deg(const int* __restrict__ dst, int E,
                                             unsigned* __restrict__ deg) {
  int e = blockIdx.x * 256 + threadIdx.x;
  if (e < E) atomicAdd(&deg[dst[e]], 1u);
}

// ---------------- CSR build: blocksum -> scan partials -> rowptr(+dis) -> fill ----------------
__global__ __launch_bounds__(256) void k_blocksum(const unsigned* __restrict__ deg,
                                                  unsigned* __restrict__ partial, int n) {
  __shared__ unsigned s[256];
  int t = threadIdx.x;
  int i = blockIdx.x * 256 + t;
  s[t] = (i < n) ? deg[i] : 0u;
  __syncthreads();
  for (int off = 128; off; off >>= 1) {
    if (t < off) s[t] += s[t + off];
    __syncthreads();
  }
  if (!t) partial[blockIdx.x] = s[0];
}

__global__ __launch_bounds__(512) void k_scanpart(unsigned* __restrict__ partial, int nb) {
  __shared__ unsigned s[512];
  int t = threadIdx.x;
  unsigned v = (t < nb) ? partial[t] : 0u;
  s[t] = v;
  __syncthreads();
  for (int off = 1; off < 512; off <<= 1) {
    unsigned add = (t >= off) ? s[t - off] : 0u;
    __syncthreads();
    s[t] += add;
    __syncthreads();
  }
  if (t < nb) partial[t] = s[t] - v;  // exclusive
}

__global__ __launch_bounds__(256) void k_rowptr(const unsigned* __restrict__ deg,
                                                const unsigned* __restrict__ partial, int n,
                                                int* __restrict__ rowptr,
                                                int* __restrict__ cursor,
                                                float* __restrict__ dis) {
  __shared__ unsigned s[256];
  int t = threadIdx.x;
  int i = blockIdx.x * 256 + t;
  unsigned v = (i < n) ? deg[i] : 0u;
  s[t] = v;
  __syncthreads();
  for (int off = 1; off < 256; off <<= 1) {
    unsigned add = (t >= off) ? s[t - off] : 0u;
    __syncthreads();
    s[t] += add;
    __syncthreads();
  }
  unsigned excl = s[t] - v + partial[blockIdx.x];
  if (i <= n) {
    rowptr[i] = (int)excl;
    if (i < n) {
      cursor[i] = (int)excl;
      dis[i] = rsqrtf((float)v + 1.0f);
    }
  }
}

__global__ __launch_bounds__(256) void k_fill(const int* __restrict__ src,
                                              const int* __restrict__ dst, int E,
                                              int* __restrict__ cursor,
                                              int* __restrict__ adj) {
  int e = blockIdx.x * 256 + threadIdx.x;
  if (e < E) {
    int d = dst[e];
    int p = atomicAdd(&cursor[d], 1);
    adj[p] = src[e];
  }
}

// ---------------- W prep: Wt[n][k] f16 from W[k][n] f32, both GCN weights ----------------
__global__ __launch_bounds__(256) void k_wprep(const float* __restrict__ W1,
                                               const float* __restrict__ W2,
                                               __half* __restrict__ Wt1,
                                               __half* __restrict__ Wt2) {
  const float* W = blockIdx.x ? W2 : W1;
  __half* Wt = blockIdx.x ? Wt2 : Wt1;
  for (int q = threadIdx.x; q < 16384; q += 256) {
    int n = q >> 7, k = q & 127;
    Wt[q] = __float2half(W[k * 128 + n]);
  }
}

// ---------------- MFMA f16 GEMM: hh[M,128] = (X[M,128] @ W) * dis[row], f16 out ----------------
// LDS XOR-swizzle (byte ^= (row&7)<<4) on both tiles; Wt pre-transposed [n][k].
__global__ __launch_bounds__(256) void k_mgemm(const float* __restrict__ X,
                                               const __half* __restrict__ Wt, int M,
                                               const float* __restrict__ dis,
                                               __half* __restrict__ hh) {
  __shared__ __align__(16) char lds[48 * 1024];
  char* As = lds;              // 64 x 128 f16 = 16 KB
  char* Bs = lds + 16 * 1024;  // 128 x 128 f16 = 32 KB
  const int t = threadIdx.x;
  const int row0 = blockIdx.x * 64;

  // stage Wt -> Bs (swizzled)
#pragma unroll
  for (int rep = 0; rep < 16; rep++) {
    int q = t + rep * 256;               // uint2 index (4 halfs), 4096 total
    int r = q >> 5, c8 = (q & 31) * 8;   // byte col
    uint2 v = *(const uint2*)((const char*)Wt + r * 256 + c8);
    *(uint2*)(Bs + ((r * 256 + c8) ^ ((r & 7) << 4))) = v;
  }
  // stage X -> As (f32 -> f16, swizzled)
#pragma unroll
  for (int rep = 0; rep < 8; rep++) {
    int q = t + rep * 256;               // float4 index, 2048 total
    int r = q >> 5, c4 = (q & 31) * 4;   // f32 col
    int gr = row0 + r;
    float4 xv = make_float4(0.f, 0.f, 0.f, 0.f);
    if (gr < M) xv = *(const float4*)&X[(size_t)gr * 128 + c4];
    __half2 h0 = __floats2half2_rn(xv.x, xv.y);
    __half2 h1 = __floats2half2_rn(xv.z, xv.w);
    uint2 pk;
    pk.x = *(unsigned*)&h0;
    pk.y = *(unsigned*)&h1;
    *(uint2*)(As + ((r * 256 + c4 * 2) ^ ((r & 7) << 4))) = pk;
  }
  __syncthreads();

  const int w = t >> 6, l = t & 63;
  const int lr = l & 15, lk = l >> 4;  // lr: row/col in tile, lk: k-group 0..3
  f32x4 acc[8] = {};
#pragma unroll
  for (int s = 0; s < 4; s++) {  // K step of 32
    int arow = w * 16 + lr;
    f16x8 a = *(const f16x8*)(As + ((arow * 256 + lk * 16 + s * 64) ^ ((arow & 7) << 4)));
#pragma unroll
    for (int nt = 0; nt < 8; nt++) {
      int brow = nt * 16 + lr;
      f16x8 b = *(const f16x8*)(Bs + ((brow * 256 + lk * 16 + s * 64) ^ ((brow & 7) << 4)));
      acc[nt] = __builtin_amdgcn_mfma_f32_16x16x32_f16(a, b, acc[nt], 0, 0, 0);
    }
  }
  // epilogue: D row=(lk*4+j), col=lr within tile
  float ddv[4];
  int rowb = row0 + w * 16 + lk * 4;
#pragma unroll
  for (int j = 0; j < 4; j++) ddv[j] = (rowb + j < M) ? dis[rowb + j] : 0.f;
#pragma unroll
  for (int nt = 0; nt < 8; nt++) {
#pragma unroll
    for (int j = 0; j < 4; j++) {
      int row = rowb + j;
      if (row < M) hh[(size_t)row * 128 + nt * 16 + lr] = __float2half(acc[nt][j] * ddv[j]);
    }
  }
}

// ---------------- GCN aggregation: CSR gather, wave/dst (R3 layout) + ILP-4 ----------------
// 64 lanes each own one half2 column pair; 4 independent neighbor-row loads in flight.
// FIN 1: out = x1 row = relu(dis*sum + b)                 [NG,128] fp32
// FIN 2: out = att row (8 scores) = relu-row . watt       [NG,8]
template <int FIN>
__global__ __launch_bounds__(256) void k_gather(const __half* __restrict__ hh,
                                                const int* __restrict__ rowptr,
                                                const int* __restrict__ adj,
                                                const float* __restrict__ dis,
                                                const float* __restrict__ b,
                                                const float* __restrict__ watt,
                                                float* __restrict__ out, int n) {
  int wid = threadIdx.x >> 6;
  int lane = threadIdx.x & 63;
  int d = blockIdx.x * 4 + wid;
  if (d >= n) return;
  int p0 = rowptr[d], p1 = rowptr[d + 1];
  int c = lane * 2;
  float2 s;
  {
    unsigned v = *(const unsigned*)&hh[(size_t)d * 128 + c];  // self loop
    s = __half22float2(*(__half2*)&v);
  }
  for (int base = p0; base < p1; base += 64) {
    int remain = p1 - base;
    int m = remain < 64 ? remain : 64;
    int idx = (lane < m) ? adj[base + lane] : 0;
    int j = 0;
    for (; j + 4 <= m; j += 4) {
      int nb0 = __shfl(idx, j);
      int nb1 = __shfl(idx, j + 1);
      int nb2 = __shfl(idx, j + 2);
      int nb3 = __shfl(idx, j + 3);
      unsigned v0 = *(const unsigned*)&hh[(size_t)nb0 * 128 + c];
      unsigned v1 = *(const unsigned*)&hh[(size_t)nb1 * 128 + c];
      unsigned v2 = *(const unsigned*)&hh[(size_t)nb2 * 128 + c];
      unsigned v3 = *(const unsigned*)&hh[(size_t)nb3 * 128 + c];
      float2 f0 = __half22float2(*(__half2*)&v0);
      float2 f1 = __half22float2(*(__half2*)&v1);
      float2 f2 = __half22float2(*(__half2*)&v2);
      float2 f3 = __half22float2(*(__half2*)&v3);
      s.x += (f0.x + f1.x) + (f2.x + f3.x);
      s.y += (f0.y + f1.y) + (f2.y + f3.y);
    }
    for (; j < m; j++) {
      int nb = __shfl(idx, j);
      unsigned v = *(const unsigned*)&hh[(size_t)nb * 128 + c];
      float2 f = __half22float2(*(__half2*)&v);
      s.x += f.x;
      s.y += f.y;
    }
  }
  float dd = dis[d];
  float x0 = fmaxf(dd * s.x + b[c], 0.f);
  float x1v = fmaxf(dd * s.y + b[c + 1], 0.f);
  if (FIN == 1) {
    *(float2*)&out[(size_t)d * 128 + c] = make_float2(x0, x1v);
  } else {
    float p[8];
    const float* w0 = &watt[c * 8];
#pragma unroll
    for (int h = 0; h < 8; h++) p[h] = x0 * w0[h] + x1v * w0[8 + h];
#pragma unroll
    for (int mm = 32; mm; mm >>= 1) {
#pragma unroll
      for (int h = 0; h < 8; h++) p[h] += __shfl_xor(p[h], mm);
    }
    if (lane == 0) {
      *(float4*)&out[(size_t)d * 8] = make_float4(p[0], p[1], p[2], p[3]);
      *(float4*)&out[(size_t)d * 8 + 4] = make_float4(p[4], p[5], p[6], p[7]);
    }
  }
}

// ---------------- fp32 GEMM for GAT hs (f16 out): X[M,128]@W[128,512] + fused a_s ----------------
__global__ __launch_bounds__(256) void k_gemm(const float* __restrict__ X,
                                              const float* __restrict__ W, int M, int N,
                                              __half* __restrict__ out,
                                              const float* __restrict__ atts,
                                              float* __restrict__ a_s) {
  __shared__ float Ws[128][128];
  __shared__ float Xs[32][128];
  const int t = threadIdx.x;
  const int row0 = blockIdx.x * 32;
  const int col0 = blockIdx.y * 128;

  for (int i = t; i < 128 * 32; i += 256) {
    int k = i >> 5;
    int c = (i & 31) << 2;
    *(float4*)&Ws[k][c] = *(const float4*)&W[(size_t)k * N + col0 + c];
  }
  for (int i = t; i < 32 * 32; i += 256) {
    int r = i >> 5;
    int c = (i & 31) << 2;
    int gr = row0 + r;
    float4 v = make_float4(0.f, 0.f, 0.f, 0.f);
    if (gr < M) v = *(const float4*)&X[(size_t)gr * 128 + c];
    *(float4*)&Xs[r][c] = v;
  }
  __syncthreads();

  const int c4 = (t & 31) * 4;
  const int r0 = (t >> 5) * 4;
  float acc[4][4];
#pragma unroll
  for (int r = 0; r < 4; r++)
#pragma unroll
    for (int j = 0; j < 4; j++) acc[r][j] = 0.f;

  for (int k = 0; k < 128; k += 4) {
    float4 wv[4];
#pragma unroll
    for (int kk = 0; kk < 4; kk++) wv[kk] = *(const float4*)&Ws[k + kk][c4];
#pragma unroll
    for (int r = 0; r < 4; r++) {
      float4 xv = *(const float4*)&Xs[r0 + r][k];
      const float* xp = (const float*)&xv;
#pragma unroll
      for (int kk = 0; kk < 4; kk++) {
        float x = xp[kk];
        acc[r][0] += x * wv[kk].x;
        acc[r][1] += x * wv[kk].y;
        acc[r][2] += x * wv[kk].z;
        acc[r][3] += x * wv[kk].w;
      }
    }
  }

  const int h = blockIdx.y;
  float4 av = *(const float4*)&atts[h * 128 + c4];
  float p[4];
#pragma unroll
  for (int r = 0; r < 4; r++) {
    int g = row0 + r0 + r;
    if (g < M) {
      __half2 h01 = __floats2half2_rn(acc[r][0], acc[r][1]);
      __half2 h23 = __floats2half2_rn(acc[r][2], acc[r][3]);
      uint2 pk;
      pk.x = *(unsigned*)&h01;
      pk.y = *(unsigned*)&h23;
      *(uint2*)&out[(size_t)g * N + col0 + c4] = pk;
    }
    p[r] = acc[r][0] * av.x + acc[r][1] * av.y + acc[r][2] * av.z + acc[r][3] * av.w;
  }
#pragma unroll
  for (int m = 1; m < 32; m <<= 1) {
#pragma unroll
    for (int r = 0; r < 4; r++) p[r] += __shfl_xor(p[r], m);
  }
  if ((t & 31) == 0) {
#pragma unroll
    for (int r = 0; r < 4; r++) {
      int g = row0 + r0 + r;
      if (g < M) a_s[(size_t)g * 4 + h] = p[r];
    }
  }
}

// ---------------- make w_att: watt[c][slot] slot 0..3 drug, 4..7 disease ----------------
__global__ __launch_bounds__(256) void k_watt(const float* __restrict__ wd,
                                              const float* __restrict__ attd_d,
                                              const float* __restrict__ wc,
                                              const float* __restrict__ attd_c,
                                              float* __restrict__ watt) {
  int t = threadIdx.x;
  for (int slot = t; slot < 1024; slot += 256) {
    int i = slot >> 3, s8 = slot & 7;
    const float* W = (s8 < 4) ? wd : wc;
    const float* A = (s8 < 4) ? attd_d : attd_c;
    int h = s8 & 3;
    float s = 0.f;
    for (int cc = 0; cc < 128; cc++) s += W[(size_t)i * 512 + h * 128 + cc] * A[h * 128 + cc];
    watt[i * 8 + s8] = s;
  }
}

// ---------------- GAT edge passes, both graphs in one launch ----------------
// PASS 2: denom[d] += exp(e);  PASS 3: wsrc[s] += exp(e)/denom[d]
template <int PASS>
__global__ __launch_bounds__(256) void k_edge(const int* __restrict__ ed, int Ed_,
                                              const float* __restrict__ asd,
                                              float* __restrict__ dend,
                                              float* __restrict__ wsd,
                                              const int* __restrict__ ec, int Ec_,
                                              const float* __restrict__ asc,
                                              float* __restrict__ denc,
                                              float* __restrict__ wsc,
                                              const float* __restrict__ att) {
  int nbd = (Ed_ + 255) >> 8;
  int blk = blockIdx.x;
  const int* src;
  const int* dst;
  const float* a_s;
  float* den;
  float* ws;
  int E, attOff, e;
  if (blk < nbd) {
    src = ed; dst = ed + Ed_; a_s = asd; den = dend; ws = wsd; E = Ed_; attOff = 0;
    e = blk * 256 + threadIdx.x;
  } else {
    src = ec; dst = ec + Ec_; a_s = asc; den = denc; ws = wsc; E = Ec_; attOff = 4;
    e = (blk - nbd) * 256 + threadIdx.x;
  }
  if (e >= E) return;
  int s = src[e], d = dst[e];
  float4 as4 = *(const float4*)&a_s[s * 4];
  float4 ad4 = *(const float4*)&att[(size_t)d * 8 + attOff];
  float v[4] = {as4.x + ad4.x, as4.y + ad4.y, as4.z + ad4.z, as4.w + ad4.w};
#pragma unroll
  for (int h = 0; h < 4; h++) {
    float eh = v[h] > 0.f ? v[h] : 0.2f * v[h];
    eh = fminf(eh, 50.f);
    if (PASS == 2) {
      atomAddF(&den[(size_t)d * 4 + h], __expf(eh));
    } else {
      float al = __expf(eh) / (den[(size_t)d * 4 + h] + 1e-16f);
      atomAddF(&ws[(size_t)s * 4 + h], al);
    }
  }
}

// ---------------- weighted column sums (f16 hs), both graphs in one launch ----------------
__global__ __launch_bounds__(512) void k_wsum(const __half* __restrict__ hs_d,
                                              const float* __restrict__ wsrc_d,
                                              float* __restrict__ S_d, int Nd,
                                              const __half* __restrict__ hs_c,
                                              const float* __restrict__ wsrc_c,
                                              float* __restrict__ S_c, int Nc) {
  int nbd = (Nd + 63) >> 6;
  int blk = blockIdx.x;
  const __half* hs;
  const float* wsrc;
  float* S;
  int r0, N;
  if (blk < nbd) { hs = hs_d; wsrc = wsrc_d; S = S_d; N = Nd; r0 = blk * 64; }
  else { hs = hs_c; wsrc = wsrc_c; S = S_c; N = Nc; r0 = (blk - nbd) * 64; }
  int t = threadIdx.x;  // 0..511 = h*128+c
  int h = t >> 7;
  int r1 = min(r0 + 64, N);
  float acc = 0.f;
  for (int r = r0; r < r1; r++) acc += wsrc[r * 4 + h] * __half2float(hs[(size_t)r * 512 + t]);
  atomAddF(&S[t], acc);
}

__global__ __launch_bounds__(128) void k_colsum(const float* __restrict__ xd,
                                                float* __restrict__ od, int Nd,
                                                const float* __restrict__ xc,
                                                float* __restrict__ oc, int Nc) {
  int nbd = (Nd + 127) >> 7;
  int blk = blockIdx.x;
  const float* x;
  float* o;
  int r0, N;
  if (blk < nbd) { x = xd; o = od; N = Nd; r0 = blk * 128; }
  else { x = xc; o = oc; N = Nc; r0 = (blk - nbd) * 128; }
  int c = threadIdx.x;
  int r1 = min(r0 + 128, N);
  float acc = 0.f;
  for (int r = r0; r < r1; r++) acc += x[(size_t)r * 128 + c];
  atomAddF(&o[c], acc);
}

// ---------------- final fuse ----------------
__global__ __launch_bounds__(128) void k_final(const float* __restrict__ S_d,
                                               const float* __restrict__ S_c,
                                               const float* __restrict__ bdsum,
                                               const float* __restrict__ bcsum,
                                               const float* __restrict__ bd_bias,
                                               const float* __restrict__ bc_bias,
                                               const float* __restrict__ fuse_w,
                                               const float* __restrict__ fuse_b,
                                               float* __restrict__ out) {
  __shared__ float cat[384];
  int t = threadIdx.x;
  float sd = S_d[t] + S_d[128 + t] + S_d[256 + t] + S_d[384 + t];
  float sc = S_c[t] + S_c[128 + t] + S_c[256 + t] + S_c[384 + t];
  const float inv = 1.0f / (4.0f * (float)NG);
  cat[t] = 0.5f * (sd * inv + bd_bias[t] + sc * inv + bc_bias[t]);
  cat[128 + t] = bdsum[t] * (1.0f / (float)NDR);
  cat[256 + t] = bcsum[t] * (1.0f / (float)NDI);
  __syncthreads();
  float o = fuse_b[t];
  for (int k = 0; k < 384; k++) o += cat[k] * fuse_w[k * 128 + t];
  out[t] = o;
}

// ---------------- host launch ----------------
static inline int cdiv(int a, int b) { return (a + b - 1) / b; }

extern "C" void kernel_launch(void* const* d_in, const int* in_sizes, int n_in,
                              void* d_out, int out_size, void* d_ws, size_t ws_size,
                              hipStream_t stream) {
  const float* gene_nodes   = (const float*)d_in[0];
  const int*   drug_edges   = (const int*)d_in[1];
  const int*   dise_edges   = (const int*)d_in[2];
  const int*   gene_edges   = (const int*)d_in[3];
  const float* gcn1_w       = (const float*)d_in[4];
  const float* gcn1_b       = (const float*)d_in[5];
  const float* gcn2_w       = (const float*)d_in[6];
  const float* gcn2_b       = (const float*)d_in[7];
  const float* drug_embed   = (const float*)d_in[8];
  const float* dise_embed   = (const float*)d_in[9];
  const float* gat_d_w      = (const float*)d_in[10];
  const float* gat_d_att_s  = (const float*)d_in[11];
  const float* gat_d_att_d  = (const float*)d_in[12];
  const float* gat_d_b      = (const float*)d_in[13];
  const float* gat_c_w      = (const float*)d_in[14];
  const float* gat_c_att_s  = (const float*)d_in[15];
  const float* gat_c_att_d  = (const float*)d_in[16];
  const float* gat_c_b      = (const float*)d_in[17];
  const float* fuse_w       = (const float*)d_in[18];
  const float* fuse_b       = (const float*)d_in[19];
  const int Ed = in_sizes[1] / 2;
  const int Ec = in_sizes[2] / 2;
  const int Eg = in_sizes[3] / 2;
  float* out = (float*)d_out;
  (void)n_in; (void)out_size; (void)ws_size;

  const int NBLK = cdiv(NG, 256);  // 391 scan blocks

  // workspace layout (zero-init region first, single memset)
  char* w = (char*)d_ws;
  auto alloc = [&](size_t n) {
    char* p = w;
    w += (n + 511) & ~(size_t)511;
    return p;
  };
  char* z0 = w;
  unsigned* deg     = (unsigned*)alloc((size_t)NG * 4);
  float* denom_d    = (float*)alloc((size_t)NG * 16);
  float* denom_c    = (float*)alloc((size_t)NG * 16);
  float* wsrc_d     = (float*)alloc((size_t)NDR * 16);
  float* wsrc_c     = (float*)alloc((size_t)NDI * 16);
  float* S_d        = (float*)alloc(512 * 4);
  float* S_c        = (float*)alloc(512 * 4);
  float* bdsum      = (float*)alloc(512);
  float* bcsum      = (float*)alloc(512);
  size_t zbytes = (size_t)(w - z0);
  float* dis        = (float*)alloc((size_t)NG * 4);
  float* watt       = (float*)alloc(128 * 8 * 4);
  float* att        = (float*)alloc((size_t)NG * 8 * 4);
  float* a_s_d      = (float*)alloc((size_t)NDR * 16);
  float* a_s_c      = (float*)alloc((size_t)NDI * 16);
  unsigned* partial = (unsigned*)alloc((size_t)512 * 4);
  int* rowptr       = (int*)alloc((size_t)(NG + 1) * 4);
  int* cursor       = (int*)alloc((size_t)NG * 4);
  int* adj          = (int*)alloc((size_t)Eg * 4);
  __half* Wt1       = (__half*)alloc((size_t)128 * 128 * 2);
  __half* Wt2       = (__half*)alloc((size_t)128 * 128 * 2);
  __half* hh        = (__half*)alloc((size_t)NG * 128 * 2);
  float* x1         = (float*)alloc((size_t)NG * 128 * 4);
  // hs buffers (f16) alias x1 (x1 is dead after GCN2 GEMM reads it)
  __half* hs_d = (__half*)x1;
  __half* hs_c = (__half*)x1 + (size_t)NDR * 512;

  hipMemsetAsync(z0, 0, zbytes, stream);

  // degree + normalization + CSR (shared by both GCN layers) + weight prep
  k_deg<<<cdiv(Eg, 256), 256, 0, stream>>>(gene_edges + Eg, Eg, deg);
  k_blocksum<<<NBLK, 256, 0, stream>>>(deg, partial, NG);
  k_scanpart<<<1, 512, 0, stream>>>(partial, NBLK);
  k_rowptr<<<NBLK, 256, 0, stream>>>(deg, partial, NG, rowptr, cursor, dis);
  k_fill<<<cdiv(Eg, 256), 256, 0, stream>>>(gene_edges, gene_edges + Eg, Eg, cursor, adj);
  k_wprep<<<2, 256, 0, stream>>>(gcn1_w, gcn2_w, Wt1, Wt2);
  k_watt<<<1, 256, 0, stream>>>(gat_d_w, gat_d_att_d, gat_c_w, gat_c_att_d, watt);

  // GCN layer 1: MFMA GEMM (f16 out, pre-scaled by dis[src]) -> gather(+relu+bias)
  k_mgemm<<<cdiv(NG, 64), 256, 0, stream>>>(gene_nodes, Wt1, NG, dis, hh);
  k_gather<1><<<cdiv(NG, 4), 256, 0, stream>>>(hh, rowptr, adj, dis, gcn1_b, nullptr, x1, NG);

  // GCN layer 2: MFMA GEMM -> gather(+relu+bias+att-score epilogue); x2 never materialized
  k_mgemm<<<cdiv(NG, 64), 256, 0, stream>>>(x1, Wt2, NG, dis, hh);
  k_gather<2><<<cdiv(NG, 4), 256, 0, stream>>>(hh, rowptr, adj, dis, gcn2_b, watt, att, NG);

  // GAT source transforms with fused a_s epilogue (hs aliases x1 — stream-ordered)
  k_gemm<<<dim3(cdiv(NDR, 32), 4), 256, 0, stream>>>(drug_embed, gat_d_w, NDR, 512, hs_d, gat_d_att_s, a_s_d);
  k_gemm<<<dim3(cdiv(NDI, 32), 4), 256, 0, stream>>>(dise_embed, gat_c_w, NDI, 512, hs_c, gat_c_att_s, a_s_c);

  // GAT softmax edge passes (both graphs per launch)
  int nbe = cdiv(Ed, 256) + cdiv(Ec, 256);
  k_edge<2><<<nbe, 256, 0, stream>>>(drug_edges, Ed, a_s_d, denom_d, wsrc_d,
                                     dise_edges, Ec, a_s_c, denom_c, wsrc_c, att);
  k_edge<3><<<nbe, 256, 0, stream>>>(drug_edges, Ed, a_s_d, denom_d, wsrc_d,
                                     dise_edges, Ec, a_s_c, denom_c, wsrc_c, att);

  // weighted column sums + embedding means
  k_wsum<<<cdiv(NDR, 64) + cdiv(NDI, 64), 512, 0, stream>>>(hs_d, wsrc_d, S_d, NDR,
                                                            hs_c, wsrc_c, S_c, NDI);
  k_colsum<<<cdiv(NDR, 128) + cdiv(NDI, 128), 128, 0, stream>>>(drug_embed, bdsum, NDR,
                                                                dise_embed, bcsum, NDI);

  // final fuse
  k_final<<<1, 128, 0, stream>>>(S_d, S_c, bdsum, bcsum, gat_d_b, gat_c_b, fuse_w, fuse_b, out);
}

// Round 6
// 549.522 us; speedup vs baseline: 7.7478x; 1.2496x over previous
//
#include <hip/hip_runtime.h>
#include <hip/hip_fp16.h>

#define NG 100000
#define NDR 10000
#define NDI 5000

typedef _Float16 f16x8 __attribute__((ext_vector_type(8)));
typedef float f32x4 __attribute__((ext_vector_type(4)));

__device__ __forceinline__ void atomAddF(float* p, float v) { unsafeAtomicAdd(p, v); }

// ---------------- degree (gene graph) ----------------
__global__ __launch_bounds__(256) void k_deg(const int* __restrict__ dst, int E,
                                             unsigned* __restrict__ deg) {
  int e = blockIdx.x * 256 + threadIdx.x;
  if (e < E) atomicAdd(&deg[dst[e]], 1u);
}

// ---------------- degree (bipartite, both graphs, both directions) ----------------
// degB layout: [Ddst NG][Cdst NG][Dsrc NDR][Csrc NDI]
__global__ __launch_bounds__(256) void k_degB(const int* __restrict__ de, int Ed_,
                                              const int* __restrict__ ce, int Ec_,
                                              unsigned* __restrict__ degB) {
  int nbd = (Ed_ + 255) >> 8;
  int blk = blockIdx.x;
  if (blk < nbd) {
    int e = blk * 256 + threadIdx.x;
    if (e < Ed_) {
      atomicAdd(&degB[de[Ed_ + e]], 1u);             // Ddst
      atomicAdd(&degB[2 * NG + de[e]], 1u);          // Dsrc
    }
  } else {
    int e = (blk - nbd) * 256 + threadIdx.x;
    if (e < Ec_) {
      atomicAdd(&degB[NG + ce[Ec_ + e]], 1u);        // Cdst
      atomicAdd(&degB[2 * NG + NDR + ce[e]], 1u);    // Csrc
    }
  }
}

// ---------------- scan helpers ----------------
__global__ __launch_bounds__(256) void k_blocksum(const unsigned* __restrict__ deg,
                                                  unsigned* __restrict__ partial, int n) {
  __shared__ unsigned s[256];
  int t = threadIdx.x;
  int i = blockIdx.x * 256 + t;
  s[t] = (i < n) ? deg[i] : 0u;
  __syncthreads();
  for (int off = 128; off; off >>= 1) {
    if (t < off) s[t] += s[t + off];
    __syncthreads();
  }
  if (!t) partial[blockIdx.x] = s[0];
}

__global__ __launch_bounds__(512) void k_scanpart(unsigned* __restrict__ partial, int nb) {
  __shared__ unsigned s[512];
  int t = threadIdx.x;
  unsigned v = (t < nb) ? partial[t] : 0u;
  s[t] = v;
  __syncthreads();
  for (int off = 1; off < 512; off <<= 1) {
    unsigned add = (t >= off) ? s[t - off] : 0u;
    __syncthreads();
    s[t] += add;
    __syncthreads();
  }
  if (t < nb) partial[t] = s[t] - v;  // exclusive
}

__global__ __launch_bounds__(256) void k_rowptr(const unsigned* __restrict__ deg,
                                                const unsigned* __restrict__ partial, int n,
                                                int* __restrict__ rowptr,
                                                int* __restrict__ cursor,
                                                float* __restrict__ dis) {
  __shared__ unsigned s[256];
  int t = threadIdx.x;
  int i = blockIdx.x * 256 + t;
  unsigned v = (i < n) ? deg[i] : 0u;
  s[t] = v;
  __syncthreads();
  for (int off = 1; off < 256; off <<= 1) {
    unsigned add = (t >= off) ? s[t - off] : 0u;
    __syncthreads();
    s[t] += add;
    __syncthreads();
  }
  unsigned excl = s[t] - v + partial[blockIdx.x];
  if (i <= n) {
    rowptr[i] = (int)excl;
    if (i < n) {
      cursor[i] = (int)excl;
      dis[i] = rsqrtf((float)v + 1.0f);
    }
  }
}

// 1024 elems/block variant (4/thread) for the 215K-node bipartite scan domain
__global__ __launch_bounds__(256) void k_blocksum4(const unsigned* __restrict__ deg,
                                                   unsigned* __restrict__ partial, int n) {
  __shared__ unsigned s[256];
  int t = threadIdx.x;
  int base = blockIdx.x * 1024 + t * 4;
  unsigned v = 0;
  if (base + 3 < n) {
    uint4 u = *(const uint4*)&deg[base];
    v = u.x + u.y + u.z + u.w;
  } else {
    for (int j = 0; j < 4; j++)
      if (base + j < n) v += deg[base + j];
  }
  s[t] = v;
  __syncthreads();
  for (int off = 128; off; off >>= 1) {
    if (t < off) s[t] += s[t + off];
    __syncthreads();
  }
  if (!t) partial[blockIdx.x] = s[0];
}

__global__ __launch_bounds__(256) void k_rowptr4(const unsigned* __restrict__ deg,
                                                 const unsigned* __restrict__ partial, int n,
                                                 int* __restrict__ rowptr,
                                                 int* __restrict__ cursor) {
  __shared__ unsigned s[256];
  int t = threadIdx.x;
  int base = blockIdx.x * 1024 + t * 4;
  unsigned v[4] = {0u, 0u, 0u, 0u};
  if (base + 3 < n) {
    uint4 u = *(const uint4*)&deg[base];
    v[0] = u.x; v[1] = u.y; v[2] = u.z; v[3] = u.w;
  } else {
    for (int j = 0; j < 4; j++)
      if (base + j < n) v[j] = deg[base + j];
  }
  unsigned sum4 = v[0] + v[1] + v[2] + v[3];
  s[t] = sum4;
  __syncthreads();
  for (int off = 1; off < 256; off <<= 1) {
    unsigned add = (t >= off) ? s[t - off] : 0u;
    __syncthreads();
    s[t] += add;
    __syncthreads();
  }
  unsigned e = s[t] - sum4 + partial[blockIdx.x];
  for (int j = 0; j < 4; j++) {
    int i = base + j;
    if (i < n) {
      rowptr[i] = (int)e;
      cursor[i] = (int)e;
      if (i == n - 1) rowptr[n] = (int)(e + v[j]);
      e += v[j];
    }
  }
}

// ---------------- fills ----------------
__global__ __launch_bounds__(256) void k_fill(const int* __restrict__ src,
                                              const int* __restrict__ dst, int E,
                                              int* __restrict__ cursor,
                                              int* __restrict__ adj) {
  int e = blockIdx.x * 256 + threadIdx.x;
  if (e < E) {
    int d = dst[e];
    int p = atomicAdd(&cursor[d], 1);
    adj[p] = src[e];
  }
}

__global__ __launch_bounds__(256) void k_fillB(const int* __restrict__ de, int Ed_,
                                               const int* __restrict__ ce, int Ec_,
                                               int* __restrict__ cursorB,
                                               int* __restrict__ adjB) {
  int nbd = (Ed_ + 255) >> 8;
  int blk = blockIdx.x;
  if (blk < nbd) {
    int e = blk * 256 + threadIdx.x;
    if (e < Ed_) {
      int s = de[e], d = de[Ed_ + e];
      int p = atomicAdd(&cursorB[d], 1);
      adjB[p] = s;
      int p2 = atomicAdd(&cursorB[2 * NG + s], 1);
      adjB[p2] = d;
    }
  } else {
    int e = (blk - nbd) * 256 + threadIdx.x;
    if (e < Ec_) {
      int s = ce[e], d = ce[Ec_ + e];
      int p = atomicAdd(&cursorB[NG + d], 1);
      adjB[p] = s;
      int p2 = atomicAdd(&cursorB[2 * NG + NDR + s], 1);
      adjB[p2] = d;
    }
  }
}

// ---------------- W prep: transpose all weights to f16 [n][k] ----------------
__global__ __launch_bounds__(256) void k_wprep(const float* __restrict__ W1,
                                               const float* __restrict__ W2,
                                               const float* __restrict__ Wd,
                                               const float* __restrict__ Wc,
                                               __half* __restrict__ Wt1,
                                               __half* __restrict__ Wt2,
                                               __half* __restrict__ Wtd,
                                               __half* __restrict__ Wtc) {
  int blk = blockIdx.x;
  const float* W;
  __half* Wt;
  int N, base;
  if (blk == 0) { W = W1; Wt = Wt1; N = 128; base = 0; }
  else if (blk == 1) { W = W2; Wt = Wt2; N = 128; base = 0; }
  else if (blk < 6) { W = Wd; Wt = Wtd; N = 512; base = (blk - 2) * 16384; }
  else { W = Wc; Wt = Wtc; N = 512; base = (blk - 6) * 16384; }
  for (int q = threadIdx.x; q < 16384; q += 256) {
    int qq = base + q;
    int n = qq >> 7, k = qq & 127;
    Wt[qq] = __float2half(W[(size_t)k * N + n]);
  }
}

// ---------------- MFMA f16 GEMM: hh[M,128] = (X[M,128] @ W) * dis[row], f16 out ----------------
__global__ __launch_bounds__(256) void k_mgemm(const float* __restrict__ X,
                                               const __half* __restrict__ Wt, int M,
                                               const float* __restrict__ dis,
                                               __half* __restrict__ hh) {
  __shared__ __align__(16) char lds[48 * 1024];
  char* As = lds;              // 64 x 128 f16 = 16 KB
  char* Bs = lds + 16 * 1024;  // 128 x 128 f16 = 32 KB
  const int t = threadIdx.x;
  const int row0 = blockIdx.x * 64;

#pragma unroll
  for (int rep = 0; rep < 16; rep++) {
    int q = t + rep * 256;
    int r = q >> 5, c8 = (q & 31) * 8;
    uint2 v = *(const uint2*)((const char*)Wt + r * 256 + c8);
    *(uint2*)(Bs + ((r * 256 + c8) ^ ((r & 7) << 4))) = v;
  }
#pragma unroll
  for (int rep = 0; rep < 8; rep++) {
    int q = t + rep * 256;
    int r = q >> 5, c4 = (q & 31) * 4;
    int gr = row0 + r;
    float4 xv = make_float4(0.f, 0.f, 0.f, 0.f);
    if (gr < M) xv = *(const float4*)&X[(size_t)gr * 128 + c4];
    __half2 h0 = __floats2half2_rn(xv.x, xv.y);
    __half2 h1 = __floats2half2_rn(xv.z, xv.w);
    uint2 pk;
    pk.x = *(unsigned*)&h0;
    pk.y = *(unsigned*)&h1;
    *(uint2*)(As + ((r * 256 + c4 * 2) ^ ((r & 7) << 4))) = pk;
  }
  __syncthreads();

  const int w = t >> 6, l = t & 63;
  const int lr = l & 15, lk = l >> 4;
  f32x4 acc[8] = {};
#pragma unroll
  for (int s = 0; s < 4; s++) {
    int arow = w * 16 + lr;
    f16x8 a = *(const f16x8*)(As + ((arow * 256 + lk * 16 + s * 64) ^ ((arow & 7) << 4)));
#pragma unroll
    for (int nt = 0; nt < 8; nt++) {
      int brow = nt * 16 + lr;
      f16x8 b = *(const f16x8*)(Bs + ((brow * 256 + lk * 16 + s * 64) ^ ((brow & 7) << 4)));
      acc[nt] = __builtin_amdgcn_mfma_f32_16x16x32_f16(a, b, acc[nt], 0, 0, 0);
    }
  }
  float ddv[4];
  int rowb = row0 + w * 16 + lk * 4;
#pragma unroll
  for (int j = 0; j < 4; j++) ddv[j] = (rowb + j < M) ? dis[rowb + j] : 0.f;
#pragma unroll
  for (int nt = 0; nt < 8; nt++) {
#pragma unroll
    for (int j = 0; j < 4; j++) {
      int row = rowb + j;
      if (row < M) hh[(size_t)row * 128 + nt * 16 + lr] = __float2half(acc[nt][j] * ddv[j]);
    }
  }
}

// ---------------- MFMA f16 GAT GEMM: hs[M,512] f16 + fused a_s epilogue ----------------
// blockIdx.y = head h (N column block h*128); Wt is [512][128] f16.
__global__ __launch_bounds__(256) void k_mgat(const float* __restrict__ X,
                                              const __half* __restrict__ Wt, int M,
                                              const float* __restrict__ attS,
                                              __half* __restrict__ hs,
                                              float* __restrict__ a_s) {
  __shared__ __align__(16) char lds[48 * 1024];
  char* As = lds;
  char* Bs = lds + 16 * 1024;
  const int t = threadIdx.x;
  const int row0 = blockIdx.x * 64;
  const int h = blockIdx.y;
  const __half* Wth = Wt + (size_t)h * 128 * 128;

#pragma unroll
  for (int rep = 0; rep < 16; rep++) {
    int q = t + rep * 256;
    int r = q >> 5, c8 = (q & 31) * 8;
    uint2 v = *(const uint2*)((const char*)Wth + r * 256 + c8);
    *(uint2*)(Bs + ((r * 256 + c8) ^ ((r & 7) << 4))) = v;
  }
#pragma unroll
  for (int rep = 0; rep < 8; rep++) {
    int q = t + rep * 256;
    int r = q >> 5, c4 = (q & 31) * 4;
    int gr = row0 + r;
    float4 xv = make_float4(0.f, 0.f, 0.f, 0.f);
    if (gr < M) xv = *(const float4*)&X[(size_t)gr * 128 + c4];
    __half2 h0 = __floats2half2_rn(xv.x, xv.y);
    __half2 h1 = __floats2half2_rn(xv.z, xv.w);
    uint2 pk;
    pk.x = *(unsigned*)&h0;
    pk.y = *(unsigned*)&h1;
    *(uint2*)(As + ((r * 256 + c4 * 2) ^ ((r & 7) << 4))) = pk;
  }
  __syncthreads();

  const int w = t >> 6, l = t & 63;
  const int lr = l & 15, lk = l >> 4;
  f32x4 acc[8] = {};
#pragma unroll
  for (int s = 0; s < 4; s++) {
    int arow = w * 16 + lr;
    f16x8 a = *(const f16x8*)(As + ((arow * 256 + lk * 16 + s * 64) ^ ((arow & 7) << 4)));
#pragma unroll
    for (int nt = 0; nt < 8; nt++) {
      int brow = nt * 16 + lr;
      f16x8 b = *(const f16x8*)(Bs + ((brow * 256 + lk * 16 + s * 64) ^ ((brow & 7) << 4)));
      acc[nt] = __builtin_amdgcn_mfma_f32_16x16x32_f16(a, b, acc[nt], 0, 0, 0);
    }
  }
  // attS values for this thread's columns
  float av[8];
#pragma unroll
  for (int nt = 0; nt < 8; nt++) av[nt] = attS[h * 128 + nt * 16 + lr];

  int rowb = row0 + w * 16 + lk * 4;
  float p[4] = {0.f, 0.f, 0.f, 0.f};
#pragma unroll
  for (int nt = 0; nt < 8; nt++) {
#pragma unroll
    for (int j = 0; j < 4; j++) {
      int row = rowb + j;
      if (row < M) hs[(size_t)row * 512 + h * 128 + nt * 16 + lr] = __float2half(acc[nt][j]);
      p[j] += acc[nt][j] * av[nt];
    }
  }
  // reduce over the 16-lane lr group
#pragma unroll
  for (int m = 1; m < 16; m <<= 1) {
#pragma unroll
    for (int j = 0; j < 4; j++) p[j] += __shfl_xor(p[j], m);
  }
  if (lr == 0) {
#pragma unroll
    for (int j = 0; j < 4; j++) {
      int row = rowb + j;
      if (row < M) a_s[(size_t)row * 4 + h] = p[j];
    }
  }
}

// ---------------- GCN aggregation: CSR gather, wave/dst + ILP-4 ----------------
template <int FIN>
__global__ __launch_bounds__(256) void k_gather(const __half* __restrict__ hh,
                                                const int* __restrict__ rowptr,
                                                const int* __restrict__ adj,
                                                const float* __restrict__ dis,
                                                const float* __restrict__ b,
                                                const float* __restrict__ watt,
                                                float* __restrict__ out, int n) {
  int wid = threadIdx.x >> 6;
  int lane = threadIdx.x & 63;
  int d = blockIdx.x * 4 + wid;
  if (d >= n) return;
  int p0 = rowptr[d], p1 = rowptr[d + 1];
  int c = lane * 2;
  float2 s;
  {
    unsigned v = *(const unsigned*)&hh[(size_t)d * 128 + c];  // self loop
    s = __half22float2(*(__half2*)&v);
  }
  for (int base = p0; base < p1; base += 64) {
    int remain = p1 - base;
    int m = remain < 64 ? remain : 64;
    int idx = (lane < m) ? adj[base + lane] : 0;
    int j = 0;
    for (; j + 4 <= m; j += 4) {
      int nb0 = __shfl(idx, j);
      int nb1 = __shfl(idx, j + 1);
      int nb2 = __shfl(idx, j + 2);
      int nb3 = __shfl(idx, j + 3);
      unsigned v0 = *(const unsigned*)&hh[(size_t)nb0 * 128 + c];
      unsigned v1 = *(const unsigned*)&hh[(size_t)nb1 * 128 + c];
      unsigned v2 = *(const unsigned*)&hh[(size_t)nb2 * 128 + c];
      unsigned v3 = *(const unsigned*)&hh[(size_t)nb3 * 128 + c];
      float2 f0 = __half22float2(*(__half2*)&v0);
      float2 f1 = __half22float2(*(__half2*)&v1);
      float2 f2 = __half22float2(*(__half2*)&v2);
      float2 f3 = __half22float2(*(__half2*)&v3);
      s.x += (f0.x + f1.x) + (f2.x + f3.x);
      s.y += (f0.y + f1.y) + (f2.y + f3.y);
    }
    for (; j < m; j++) {
      int nb = __shfl(idx, j);
      unsigned v = *(const unsigned*)&hh[(size_t)nb * 128 + c];
      float2 f = __half22float2(*(__half2*)&v);
      s.x += f.x;
      s.y += f.y;
    }
  }
  float dd = dis[d];
  float x0 = fmaxf(dd * s.x + b[c], 0.f);
  float x1v = fmaxf(dd * s.y + b[c + 1], 0.f);
  if (FIN == 1) {
    *(float2*)&out[(size_t)d * 128 + c] = make_float2(x0, x1v);
  } else {
    float p[8];
    const float* w0 = &watt[c * 8];
#pragma unroll
    for (int h = 0; h < 8; h++) p[h] = x0 * w0[h] + x1v * w0[8 + h];
#pragma unroll
    for (int mm = 32; mm; mm >>= 1) {
#pragma unroll
      for (int h = 0; h < 8; h++) p[h] += __shfl_xor(p[h], mm);
    }
    if (lane == 0) {
      *(float4*)&out[(size_t)d * 8] = make_float4(p[0], p[1], p[2], p[3]);
      *(float4*)&out[(size_t)d * 8 + 4] = make_float4(p[4], p[5], p[6], p[7]);
    }
  }
}

// ---------------- make w_att ----------------
__global__ __launch_bounds__(256) void k_watt(const float* __restrict__ wd,
                                              const float* __restrict__ attd_d,
                                              const float* __restrict__ wc,
                                              const float* __restrict__ attd_c,
                                              float* __restrict__ watt) {
  int t = threadIdx.x;
  for (int slot = t; slot < 1024; slot += 256) {
    int i = slot >> 3, s8 = slot & 7;
    const float* W = (s8 < 4) ? wd : wc;
    const float* A = (s8 < 4) ? attd_d : attd_c;
    int h = s8 & 3;
    float s = 0.f;
    for (int cc = 0; cc < 128; cc++) s += W[(size_t)i * 512 + h * 128 + cc] * A[h * 128 + cc];
    watt[i * 8 + s8] = s;
  }
}

// ---------------- GAT softmax pass A: denom by dst-gather (no atomics) ----------------
__global__ __launch_bounds__(256) void k_edgeA(const int* __restrict__ rowptrB,
                                               const int* __restrict__ adjB,
                                               const float* __restrict__ a_s_d,
                                               const float* __restrict__ a_s_c,
                                               const float* __restrict__ att,
                                               float* __restrict__ denom_d,
                                               float* __restrict__ denom_c) {
  int nb1 = (NG + 255) >> 8;
  int blk = blockIdx.x;
  int q = blk >= nb1;
  int d = (blk - (q ? nb1 : 0)) * 256 + threadIdx.x;
  if (d >= NG) return;
  const int* rp = rowptrB + (q ? NG : 0);
  const float* a_s = q ? a_s_c : a_s_d;
  float* den = q ? denom_c : denom_d;
  int p0 = rp[d], p1 = rp[d + 1];
  float4 ad4 = *(const float4*)&att[(size_t)d * 8 + q * 4];
  float4 acc = make_float4(0.f, 0.f, 0.f, 0.f);
  for (int p = p0; p < p1; p++) {
    int s = adjB[p];
    float4 as4 = *(const float4*)&a_s[(size_t)s * 4];
    float v0 = as4.x + ad4.x, v1 = as4.y + ad4.y, v2 = as4.z + ad4.z, v3 = as4.w + ad4.w;
    v0 = v0 > 0.f ? v0 : 0.2f * v0;
    v1 = v1 > 0.f ? v1 : 0.2f * v1;
    v2 = v2 > 0.f ? v2 : 0.2f * v2;
    v3 = v3 > 0.f ? v3 : 0.2f * v3;
    acc.x += __expf(fminf(v0, 50.f));
    acc.y += __expf(fminf(v1, 50.f));
    acc.z += __expf(fminf(v2, 50.f));
    acc.w += __expf(fminf(v3, 50.f));
  }
  *(float4*)&den[(size_t)d * 4] = acc;
}

// ---------------- GAT softmax pass B: wsrc by src-gather (wave/src, no atomics) ----------------
__global__ __launch_bounds__(256) void k_edgeB(const int* __restrict__ rowptrB,
                                               const int* __restrict__ adjB,
                                               const float* __restrict__ a_s_d,
                                               const float* __restrict__ a_s_c,
                                               const float* __restrict__ att,
                                               const float* __restrict__ denom_d,
                                               const float* __restrict__ denom_c,
                                               float* __restrict__ wsrc_d,
                                               float* __restrict__ wsrc_c) {
  int gw = (blockIdx.x * 256 + threadIdx.x) >> 6;
  int lane = threadIdx.x & 63;
  int q = gw >= NDR;
  int s = q ? gw - NDR : gw;
  if (q && s >= NDI) return;
  const int* rp = rowptrB + 2 * NG + (q ? NDR : 0);
  const float* a_s = q ? a_s_c : a_s_d;
  const float* den = q ? denom_c : denom_d;
  float* ws = q ? wsrc_c : wsrc_d;
  int p0 = rp[s], p1 = rp[s + 1];
  float4 as4 = *(const float4*)&a_s[(size_t)s * 4];
  int attoff = q * 4;
  float4 acc = make_float4(0.f, 0.f, 0.f, 0.f);
  for (int p = p0 + lane; p < p1; p += 64) {
    int d = adjB[p];
    float4 ad4 = *(const float4*)&att[(size_t)d * 8 + attoff];
    float4 dn = *(const float4*)&den[(size_t)d * 4];
    float v0 = as4.x + ad4.x, v1 = as4.y + ad4.y, v2 = as4.z + ad4.z, v3 = as4.w + ad4.w;
    v0 = v0 > 0.f ? v0 : 0.2f * v0;
    v1 = v1 > 0.f ? v1 : 0.2f * v1;
    v2 = v2 > 0.f ? v2 : 0.2f * v2;
    v3 = v3 > 0.f ? v3 : 0.2f * v3;
    acc.x += __expf(fminf(v0, 50.f)) / (dn.x + 1e-16f);
    acc.y += __expf(fminf(v1, 50.f)) / (dn.y + 1e-16f);
    acc.z += __expf(fminf(v2, 50.f)) / (dn.z + 1e-16f);
    acc.w += __expf(fminf(v3, 50.f)) / (dn.w + 1e-16f);
  }
#pragma unroll
  for (int m = 1; m < 64; m <<= 1) {
    acc.x += __shfl_xor(acc.x, m);
    acc.y += __shfl_xor(acc.y, m);
    acc.z += __shfl_xor(acc.z, m);
    acc.w += __shfl_xor(acc.w, m);
  }
  if (lane == 0) *(float4*)&ws[(size_t)s * 4] = acc;
}

// ---------------- weighted column sums (f16 hs), both graphs ----------------
__global__ __launch_bounds__(512) void k_wsum(const __half* __restrict__ hs_d,
                                              const float* __restrict__ wsrc_d,
                                              float* __restrict__ S_d, int Nd,
                                              const __half* __restrict__ hs_c,
                                              const float* __restrict__ wsrc_c,
                                              float* __restrict__ S_c, int Nc) {
  int nbd = (Nd + 63) >> 6;
  int blk = blockIdx.x;
  const __half* hs;
  const float* wsrc;
  float* S;
  int r0, N;
  if (blk < nbd) { hs = hs_d; wsrc = wsrc_d; S = S_d; N = Nd; r0 = blk * 64; }
  else { hs = hs_c; wsrc = wsrc_c; S = S_c; N = Nc; r0 = (blk - nbd) * 64; }
  int t = threadIdx.x;
  int h = t >> 7;
  int r1 = min(r0 + 64, N);
  float acc = 0.f;
  for (int r = r0; r < r1; r++) acc += wsrc[r * 4 + h] * __half2float(hs[(size_t)r * 512 + t]);
  atomAddF(&S[t], acc);
}

__global__ __launch_bounds__(128) void k_colsum(const float* __restrict__ xd,
                                                float* __restrict__ od, int Nd,
                                                const float* __restrict__ xc,
                                                float* __restrict__ oc, int Nc) {
  int nbd = (Nd + 127) >> 7;
  int blk = blockIdx.x;
  const float* x;
  float* o;
  int r0, N;
  if (blk < nbd) { x = xd; o = od; N = Nd; r0 = blk * 128; }
  else { x = xc; o = oc; N = Nc; r0 = (blk - nbd) * 128; }
  int c = threadIdx.x;
  int r1 = min(r0 + 128, N);
  float acc = 0.f;
  for (int r = r0; r < r1; r++) acc += x[(size_t)r * 128 + c];
  atomAddF(&o[c], acc);
}

// ---------------- final fuse ----------------
__global__ __launch_bounds__(128) void k_final(const float* __restrict__ S_d,
                                               const float* __restrict__ S_c,
                                               const float* __restrict__ bdsum,
                                               const float* __restrict__ bcsum,
                                               const float* __restrict__ bd_bias,
                                               const float* __restrict__ bc_bias,
                                               const float* __restrict__ fuse_w,
                                               const float* __restrict__ fuse_b,
                                               float* __restrict__ out) {
  __shared__ float cat[384];
  int t = threadIdx.x;
  float sd = S_d[t] + S_d[128 + t] + S_d[256 + t] + S_d[384 + t];
  float sc = S_c[t] + S_c[128 + t] + S_c[256 + t] + S_c[384 + t];
  const float inv = 1.0f / (4.0f * (float)NG);
  cat[t] = 0.5f * (sd * inv + bd_bias[t] + sc * inv + bc_bias[t]);
  cat[128 + t] = bdsum[t] * (1.0f / (float)NDR);
  cat[256 + t] = bcsum[t] * (1.0f / (float)NDI);
  __syncthreads();
  float o = fuse_b[t];
  for (int k = 0; k < 384; k++) o += cat[k] * fuse_w[k * 128 + t];
  out[t] = o;
}

// ---------------- host launch ----------------
static inline int cdiv(int a, int b) { return (a + b - 1) / b; }

extern "C" void kernel_launch(void* const* d_in, const int* in_sizes, int n_in,
                              void* d_out, int out_size, void* d_ws, size_t ws_size,
                              hipStream_t stream) {
  const float* gene_nodes   = (const float*)d_in[0];
  const int*   drug_edges   = (const int*)d_in[1];
  const int*   dise_edges   = (const int*)d_in[2];
  const int*   gene_edges   = (const int*)d_in[3];
  const float* gcn1_w       = (const float*)d_in[4];
  const float* gcn1_b       = (const float*)d_in[5];
  const float* gcn2_w       = (const float*)d_in[6];
  const float* gcn2_b       = (const float*)d_in[7];
  const float* drug_embed   = (const float*)d_in[8];
  const float* dise_embed   = (const float*)d_in[9];
  const float* gat_d_w      = (const float*)d_in[10];
  const float* gat_d_att_s  = (const float*)d_in[11];
  const float* gat_d_att_d  = (const float*)d_in[12];
  const float* gat_d_b      = (const float*)d_in[13];
  const float* gat_c_w      = (const float*)d_in[14];
  const float* gat_c_att_s  = (const float*)d_in[15];
  const float* gat_c_att_d  = (const float*)d_in[16];
  const float* gat_c_b      = (const float*)d_in[17];
  const float* fuse_w       = (const float*)d_in[18];
  const float* fuse_b       = (const float*)d_in[19];
  const int Ed = in_sizes[1] / 2;
  const int Ec = in_sizes[2] / 2;
  const int Eg = in_sizes[3] / 2;
  float* out = (float*)d_out;
  (void)n_in; (void)out_size; (void)ws_size;

  const int NBLK = cdiv(NG, 256);           // gene scan blocks (391)
  const int N4 = 2 * NG + NDR + NDI;        // bipartite scan domain (215000)
  const int NB4 = cdiv(N4, 1024);           // 211 max

  // workspace layout (zero-init region first, single memset)
  char* w = (char*)d_ws;
  auto alloc = [&](size_t n) {
    char* p = w;
    w += (n + 511) & ~(size_t)511;
    return p;
  };
  char* z0 = w;
  unsigned* deg     = (unsigned*)alloc((size_t)NG * 4);
  unsigned* degB    = (unsigned*)alloc((size_t)N4 * 4);
  float* S_d        = (float*)alloc(512 * 4);
  float* S_c        = (float*)alloc(512 * 4);
  float* bdsum      = (float*)alloc(512);
  float* bcsum      = (float*)alloc(512);
  size_t zbytes = (size_t)(w - z0);
  float* denom_d    = (float*)alloc((size_t)NG * 16);
  float* denom_c    = (float*)alloc((size_t)NG * 16);
  float* wsrc_d     = (float*)alloc((size_t)NDR * 16);
  float* wsrc_c     = (float*)alloc((size_t)NDI * 16);
  float* dis        = (float*)alloc((size_t)NG * 4);
  float* watt       = (float*)alloc(128 * 8 * 4);
  float* att        = (float*)alloc((size_t)NG * 8 * 4);
  float* a_s_d      = (float*)alloc((size_t)NDR * 16);
  float* a_s_c      = (float*)alloc((size_t)NDI * 16);
  unsigned* partial = (unsigned*)alloc((size_t)512 * 4);
  unsigned* partial2= (unsigned*)alloc((size_t)512 * 4);
  int* rowptr       = (int*)alloc((size_t)(NG + 1) * 4);
  int* cursor       = (int*)alloc((size_t)NG * 4);
  int* adj          = (int*)alloc((size_t)Eg * 4);
  int* rowptrB      = (int*)alloc((size_t)(N4 + 1) * 4);
  int* cursorB      = (int*)alloc((size_t)N4 * 4);
  int* adjB         = (int*)alloc((size_t)2 * (Ed + Ec) * 4);
  __half* Wt1       = (__half*)alloc((size_t)128 * 128 * 2);
  __half* Wt2       = (__half*)alloc((size_t)128 * 128 * 2);
  __half* Wtd       = (__half*)alloc((size_t)512 * 128 * 2);
  __half* Wtc       = (__half*)alloc((size_t)512 * 128 * 2);
  __half* hh        = (__half*)alloc((size_t)NG * 128 * 2);
  float* x1         = (float*)alloc((size_t)NG * 128 * 4);
  // hs buffers (f16) alias x1 (x1 is dead after GCN2 GEMM reads it)
  __half* hs_d = (__half*)x1;
  __half* hs_c = (__half*)x1 + (size_t)NDR * 512;

  hipMemsetAsync(z0, 0, zbytes, stream);

  // gene CSR + dis
  k_deg<<<cdiv(Eg, 256), 256, 0, stream>>>(gene_edges + Eg, Eg, deg);
  k_blocksum<<<NBLK, 256, 0, stream>>>(deg, partial, NG);
  k_scanpart<<<1, 512, 0, stream>>>(partial, NBLK);
  k_rowptr<<<NBLK, 256, 0, stream>>>(deg, partial, NG, rowptr, cursor, dis);
  k_fill<<<cdiv(Eg, 256), 256, 0, stream>>>(gene_edges, gene_edges + Eg, Eg, cursor, adj);

  // bipartite CSRs (by-dst and by-src, both graphs, one scan domain)
  int nbde = cdiv(Ed, 256) + cdiv(Ec, 256);
  k_degB<<<nbde, 256, 0, stream>>>(drug_edges, Ed, dise_edges, Ec, degB);
  k_blocksum4<<<NB4, 256, 0, stream>>>(degB, partial2, N4);
  k_scanpart<<<1, 512, 0, stream>>>(partial2, NB4);
  k_rowptr4<<<NB4, 256, 0, stream>>>(degB, partial2, N4, rowptrB, cursorB);
  k_fillB<<<nbde, 256, 0, stream>>>(drug_edges, Ed, dise_edges, Ec, cursorB, adjB);

  // weight prep
  k_wprep<<<10, 256, 0, stream>>>(gcn1_w, gcn2_w, gat_d_w, gat_c_w, Wt1, Wt2, Wtd, Wtc);
  k_watt<<<1, 256, 0, stream>>>(gat_d_w, gat_d_att_d, gat_c_w, gat_c_att_d, watt);

  // GCN layer 1
  k_mgemm<<<cdiv(NG, 64), 256, 0, stream>>>(gene_nodes, Wt1, NG, dis, hh);
  k_gather<1><<<cdiv(NG, 4), 256, 0, stream>>>(hh, rowptr, adj, dis, gcn1_b, nullptr, x1, NG);

  // GCN layer 2 (att-score epilogue; x2 never materialized)
  k_mgemm<<<cdiv(NG, 64), 256, 0, stream>>>(x1, Wt2, NG, dis, hh);
  k_gather<2><<<cdiv(NG, 4), 256, 0, stream>>>(hh, rowptr, adj, dis, gcn2_b, watt, att, NG);

  // GAT source transforms (MFMA, f16 hs + fused a_s); hs aliases x1 — stream-ordered
  k_mgat<<<dim3(cdiv(NDR, 64), 4), 256, 0, stream>>>(drug_embed, Wtd, NDR, gat_d_att_s, hs_d, a_s_d);
  k_mgat<<<dim3(cdiv(NDI, 64), 4), 256, 0, stream>>>(dise_embed, Wtc, NDI, gat_c_att_s, hs_c, a_s_c);

  // GAT softmax: denom by dst-gather, wsrc by src-gather (no atomics)
  k_edgeA<<<2 * cdiv(NG, 256), 256, 0, stream>>>(rowptrB, adjB, a_s_d, a_s_c, att, denom_d, denom_c);
  k_edgeB<<<cdiv((NDR + NDI) * 64, 256), 256, 0, stream>>>(rowptrB, adjB, a_s_d, a_s_c, att,
                                                           denom_d, denom_c, wsrc_d, wsrc_c);

  // weighted column sums + embedding means
  k_wsum<<<cdiv(NDR, 64) + cdiv(NDI, 64), 512, 0, stream>>>(hs_d, wsrc_d, S_d, NDR,
                                                            hs_c, wsrc_c, S_c, NDI);
  k_colsum<<<cdiv(NDR, 128) + cdiv(NDI, 128), 128, 0, stream>>>(drug_embed, bdsum, NDR,
                                                                dise_embed, bcsum, NDI);

  // final fuse
  k_final<<<1, 128, 0, stream>>>(S_d, S_c, bdsum, bcsum, gat_d_b, gat_c_b, fuse_w, fuse_b, out);
}

// Round 7
// 514.585 us; speedup vs baseline: 8.2738x; 1.0679x over previous
//
#include <hip/hip_runtime.h>
#include <hip/hip_fp16.h>

#define NG 100000
#define NDR 10000
#define NDI 5000

typedef _Float16 f16x8 __attribute__((ext_vector_type(8)));
typedef float f32x4 __attribute__((ext_vector_type(4)));

__device__ __forceinline__ void atomAddF(float* p, float v) { unsafeAtomicAdd(p, v); }

static inline int cdiv_h(int a, int b) { return (a + b - 1) / b; }

// ---------------- combined degree: [gene NG][Ddst NG][Cdst NG][Dsrc NDR][Csrc NDI] ----------------
__global__ __launch_bounds__(256) void k_degAll(const int* __restrict__ ge, int Eg_,
                                                const int* __restrict__ de, int Ed_,
                                                const int* __restrict__ ce, int Ec_,
                                                unsigned* __restrict__ deg) {
  int nb_g = (Eg_ + 255) >> 8, nb_d = (Ed_ + 255) >> 8;
  int blk = blockIdx.x;
  if (blk < nb_g) {
    int e = blk * 256 + threadIdx.x;
    if (e < Eg_) atomicAdd(&deg[ge[Eg_ + e]], 1u);
  } else if (blk < nb_g + nb_d) {
    int e = (blk - nb_g) * 256 + threadIdx.x;
    if (e < Ed_) {
      atomicAdd(&deg[NG + de[Ed_ + e]], 1u);
      atomicAdd(&deg[3 * NG + de[e]], 1u);
    }
  } else {
    int e = (blk - nb_g - nb_d) * 256 + threadIdx.x;
    if (e < Ec_) {
      atomicAdd(&deg[2 * NG + ce[Ec_ + e]], 1u);
      atomicAdd(&deg[3 * NG + NDR + ce[e]], 1u);
    }
  }
}

// ---------------- scan (1024 elems/block) ----------------
__global__ __launch_bounds__(256) void k_blocksum4(const unsigned* __restrict__ deg,
                                                   unsigned* __restrict__ partial, int n) {
  __shared__ unsigned s[256];
  int t = threadIdx.x;
  int base = blockIdx.x * 1024 + t * 4;
  unsigned v = 0;
  if (base + 3 < n) {
    uint4 u = *(const uint4*)&deg[base];
    v = u.x + u.y + u.z + u.w;
  } else {
    for (int j = 0; j < 4; j++)
      if (base + j < n) v += deg[base + j];
  }
  s[t] = v;
  __syncthreads();
  for (int off = 128; off; off >>= 1) {
    if (t < off) s[t] += s[t + off];
    __syncthreads();
  }
  if (!t) partial[blockIdx.x] = s[0];
}

__global__ __launch_bounds__(512) void k_scanpart(unsigned* __restrict__ partial, int nb) {
  __shared__ unsigned s[512];
  int t = threadIdx.x;
  unsigned v = (t < nb) ? partial[t] : 0u;
  s[t] = v;
  __syncthreads();
  for (int off = 1; off < 512; off <<= 1) {
    unsigned add = (t >= off) ? s[t - off] : 0u;
    __syncthreads();
    s[t] += add;
    __syncthreads();
  }
  if (t < nb) partial[t] = s[t] - v;  // exclusive
}

__global__ __launch_bounds__(256) void k_rowptrAll(const unsigned* __restrict__ deg,
                                                   const unsigned* __restrict__ partial, int n,
                                                   int* __restrict__ rowptr,
                                                   int* __restrict__ cursor,
                                                   float* __restrict__ dis) {
  __shared__ unsigned s[256];
  int t = threadIdx.x;
  int base = blockIdx.x * 1024 + t * 4;
  unsigned v[4] = {0u, 0u, 0u, 0u};
  if (base + 3 < n) {
    uint4 u = *(const uint4*)&deg[base];
    v[0] = u.x; v[1] = u.y; v[2] = u.z; v[3] = u.w;
  } else {
    for (int j = 0; j < 4; j++)
      if (base + j < n) v[j] = deg[base + j];
  }
  unsigned sum4 = v[0] + v[1] + v[2] + v[3];
  s[t] = sum4;
  __syncthreads();
  for (int off = 1; off < 256; off <<= 1) {
    unsigned add = (t >= off) ? s[t - off] : 0u;
    __syncthreads();
    s[t] += add;
    __syncthreads();
  }
  unsigned e = s[t] - sum4 + partial[blockIdx.x];
  for (int j = 0; j < 4; j++) {
    int i = base + j;
    if (i < n) {
      rowptr[i] = (int)e;
      cursor[i] = (int)e;
      if (i < NG) dis[i] = rsqrtf((float)v[j] + 1.0f);
      if (i == n - 1) rowptr[n] = (int)(e + v[j]);
      e += v[j];
    }
  }
}

// ---------------- combined fill ----------------
__global__ __launch_bounds__(256) void k_fillAll(const int* __restrict__ ge, int Eg_,
                                                 const int* __restrict__ de, int Ed_,
                                                 const int* __restrict__ ce, int Ec_,
                                                 int* __restrict__ cursor,
                                                 int* __restrict__ adj) {
  int nb_g = (Eg_ + 255) >> 8, nb_d = (Ed_ + 255) >> 8;
  int blk = blockIdx.x;
  if (blk < nb_g) {
    int e = blk * 256 + threadIdx.x;
    if (e < Eg_) {
      int d = ge[Eg_ + e];
      int p = atomicAdd(&cursor[d], 1);
      adj[p] = ge[e];
    }
  } else if (blk < nb_g + nb_d) {
    int e = (blk - nb_g) * 256 + threadIdx.x;
    if (e < Ed_) {
      int s = de[e], d = de[Ed_ + e];
      int p = atomicAdd(&cursor[NG + d], 1);
      adj[p] = s;
      int p2 = atomicAdd(&cursor[3 * NG + s], 1);
      adj[p2] = d;
    }
  } else {
    int e = (blk - nb_g - nb_d) * 256 + threadIdx.x;
    if (e < Ec_) {
      int s = ce[e], d = ce[Ec_ + e];
      int p = atomicAdd(&cursor[2 * NG + d], 1);
      adj[p] = s;
      int p2 = atomicAdd(&cursor[3 * NG + NDR + s], 1);
      adj[p2] = d;
    }
  }
}

// ---------------- prep: transpose weights to f16 [n][k] + watt ----------------
__global__ __launch_bounds__(256) void k_prep(const float* __restrict__ W1,
                                              const float* __restrict__ W2,
                                              const float* __restrict__ Wd,
                                              const float* __restrict__ Wc,
                                              const float* __restrict__ attd_d,
                                              const float* __restrict__ attd_c,
                                              __half* __restrict__ Wt1,
                                              __half* __restrict__ Wt2,
                                              __half* __restrict__ Wtd,
                                              __half* __restrict__ Wtc,
                                              float* __restrict__ watt) {
  int blk = blockIdx.x;
  if (blk == 10) {
    int t = threadIdx.x;
    for (int slot = t; slot < 1024; slot += 256) {
      int i = slot >> 3, s8 = slot & 7;
      const float* W = (s8 < 4) ? Wd : Wc;
      const float* A = (s8 < 4) ? attd_d : attd_c;
      int h = s8 & 3;
      float s = 0.f;
      for (int cc = 0; cc < 128; cc++) s += W[(size_t)i * 512 + h * 128 + cc] * A[h * 128 + cc];
      watt[i * 8 + s8] = s;
    }
    return;
  }
  const float* W;
  __half* Wt;
  int N, base;
  if (blk == 0) { W = W1; Wt = Wt1; N = 128; base = 0; }
  else if (blk == 1) { W = W2; Wt = Wt2; N = 128; base = 0; }
  else if (blk < 6) { W = Wd; Wt = Wtd; N = 512; base = (blk - 2) * 16384; }
  else { W = Wc; Wt = Wtc; N = 512; base = (blk - 6) * 16384; }
  for (int q = threadIdx.x; q < 16384; q += 256) {
    int qq = base + q;
    int n = qq >> 7, k = qq & 127;
    Wt[qq] = __float2half(W[(size_t)k * N + n]);
  }
}

// ---------------- MFMA f16 GEMM: hh[M,128] = (X[M,128] @ W) * dis[row], f16 out ----------------
// INF16=0: X is f32 (convert while staging); INF16=1: X is f16 (direct stage).
template <int INF16>
__global__ __launch_bounds__(256) void k_mgemm(const void* __restrict__ Xv,
                                               const __half* __restrict__ Wt, int M,
                                               const float* __restrict__ dis,
                                               __half* __restrict__ hh) {
  __shared__ __align__(16) char lds[48 * 1024];
  char* As = lds;              // 64 x 128 f16 = 16 KB
  char* Bs = lds + 16 * 1024;  // 128 x 128 f16 = 32 KB
  const int t = threadIdx.x;
  const int row0 = blockIdx.x * 64;

  // stage Wt -> Bs (16B chunks, swizzled)
#pragma unroll
  for (int rep = 0; rep < 8; rep++) {
    int q = t + rep * 256;               // uint4 index, 2048 total
    int r = q >> 4, c16 = (q & 15) * 16;
    uint4 v = *(const uint4*)((const char*)Wt + r * 256 + c16);
    *(uint4*)(Bs + ((r * 256 + c16) ^ ((r & 7) << 4))) = v;
  }
  // stage X -> As
  if (INF16 == 0) {
    const float* X = (const float*)Xv;
#pragma unroll
    for (int rep = 0; rep < 8; rep++) {
      int q = t + rep * 256;             // 4-f32 chunk index, 2048 total
      int r = q >> 5, c4 = (q & 31) * 4;
      int gr = row0 + r;
      float4 xv = make_float4(0.f, 0.f, 0.f, 0.f);
      if (gr < M) xv = *(const float4*)&X[(size_t)gr * 128 + c4];
      __half2 h0 = __floats2half2_rn(xv.x, xv.y);
      __half2 h1 = __floats2half2_rn(xv.z, xv.w);
      uint2 pk;
      pk.x = *(unsigned*)&h0;
      pk.y = *(unsigned*)&h1;
      *(uint2*)(As + ((r * 256 + c4 * 2) ^ ((r & 7) << 4))) = pk;
    }
  } else {
    const __half* X = (const __half*)Xv;
#pragma unroll
    for (int rep = 0; rep < 4; rep++) {
      int q = t + rep * 256;             // uint4 index, 1024 total
      int r = q >> 4, c16 = (q & 15) * 16;
      int gr = row0 + r;
      uint4 v = make_uint4(0u, 0u, 0u, 0u);
      if (gr < M) v = *(const uint4*)((const char*)X + (size_t)gr * 256 + c16);
      *(uint4*)(As + ((r * 256 + c16) ^ ((r & 7) << 4))) = v;
    }
  }
  __syncthreads();

  const int w = t >> 6, l = t & 63;
  const int lr = l & 15, lk = l >> 4;
  f32x4 acc[8] = {};
#pragma unroll
  for (int s = 0; s < 4; s++) {
    int arow = w * 16 + lr;
    f16x8 a = *(const f16x8*)(As + ((arow * 256 + lk * 16 + s * 64) ^ ((arow & 7) << 4)));
#pragma unroll
    for (int nt = 0; nt < 8; nt++) {
      int brow = nt * 16 + lr;
      f16x8 b = *(const f16x8*)(Bs + ((brow * 256 + lk * 16 + s * 64) ^ ((brow & 7) << 4)));
      acc[nt] = __builtin_amdgcn_mfma_f32_16x16x32_f16(a, b, acc[nt], 0, 0, 0);
    }
  }
  float ddv[4];
  int rowb = row0 + w * 16 + lk * 4;
#pragma unroll
  for (int j = 0; j < 4; j++) ddv[j] = (rowb + j < M) ? dis[rowb + j] : 0.f;
#pragma unroll
  for (int nt = 0; nt < 8; nt++) {
#pragma unroll
    for (int j = 0; j < 4; j++) {
      int row = rowb + j;
      if (row < M) hh[(size_t)row * 128 + nt * 16 + lr] = __float2half(acc[nt][j] * ddv[j]);
    }
  }
}

// ---------------- MFMA f16 GAT GEMM (drug+disease in one launch) ----------------
__global__ __launch_bounds__(256) void k_mgat(const float* __restrict__ Xd,
                                              const float* __restrict__ Xc,
                                              const __half* __restrict__ Wtd,
                                              const __half* __restrict__ Wtc,
                                              const float* __restrict__ attSd,
                                              const float* __restrict__ attSc,
                                              __half* __restrict__ hsd,
                                              __half* __restrict__ hsc,
                                              float* __restrict__ a_s_d,
                                              float* __restrict__ a_s_c) {
  __shared__ __align__(16) char lds[48 * 1024];
  char* As = lds;
  char* Bs = lds + 16 * 1024;
  const int t = threadIdx.x;
  const int nbd = (NDR + 63) >> 6;
  const int q = blockIdx.x >= nbd;
  const int bx = q ? blockIdx.x - nbd : blockIdx.x;
  const int M = q ? NDI : NDR;
  const float* X = q ? Xc : Xd;
  const __half* Wt = q ? Wtc : Wtd;
  const float* attS = q ? attSc : attSd;
  __half* hs = q ? hsc : hsd;
  float* a_s = q ? a_s_c : a_s_d;
  const int row0 = bx * 64;
  const int h = blockIdx.y;
  const __half* Wth = Wt + (size_t)h * 128 * 128;

#pragma unroll
  for (int rep = 0; rep < 8; rep++) {
    int r = (t + rep * 256) >> 4, c16 = ((t + rep * 256) & 15) * 16;
    uint4 v = *(const uint4*)((const char*)Wth + r * 256 + c16);
    *(uint4*)(Bs + ((r * 256 + c16) ^ ((r & 7) << 4))) = v;
  }
#pragma unroll
  for (int rep = 0; rep < 8; rep++) {
    int qq = t + rep * 256;
    int r = qq >> 5, c4 = (qq & 31) * 4;
    int gr = row0 + r;
    float4 xv = make_float4(0.f, 0.f, 0.f, 0.f);
    if (gr < M) xv = *(const float4*)&X[(size_t)gr * 128 + c4];
    __half2 h0 = __floats2half2_rn(xv.x, xv.y);
    __half2 h1 = __floats2half2_rn(xv.z, xv.w);
    uint2 pk;
    pk.x = *(unsigned*)&h0;
    pk.y = *(unsigned*)&h1;
    *(uint2*)(As + ((r * 256 + c4 * 2) ^ ((r & 7) << 4))) = pk;
  }
  __syncthreads();

  const int w = t >> 6, l = t & 63;
  const int lr = l & 15, lk = l >> 4;
  f32x4 acc[8] = {};
#pragma unroll
  for (int s = 0; s < 4; s++) {
    int arow = w * 16 + lr;
    f16x8 a = *(const f16x8*)(As + ((arow * 256 + lk * 16 + s * 64) ^ ((arow & 7) << 4)));
#pragma unroll
    for (int nt = 0; nt < 8; nt++) {
      int brow = nt * 16 + lr;
      f16x8 b = *(const f16x8*)(Bs + ((brow * 256 + lk * 16 + s * 64) ^ ((brow & 7) << 4)));
      acc[nt] = __builtin_amdgcn_mfma_f32_16x16x32_f16(a, b, acc[nt], 0, 0, 0);
    }
  }
  float av[8];
#pragma unroll
  for (int nt = 0; nt < 8; nt++) av[nt] = attS[h * 128 + nt * 16 + lr];

  int rowb = row0 + w * 16 + lk * 4;
  float p[4] = {0.f, 0.f, 0.f, 0.f};
#pragma unroll
  for (int nt = 0; nt < 8; nt++) {
#pragma unroll
    for (int j = 0; j < 4; j++) {
      int row = rowb + j;
      if (row < M) hs[(size_t)row * 512 + h * 128 + nt * 16 + lr] = __float2half(acc[nt][j]);
      p[j] += acc[nt][j] * av[nt];
    }
  }
#pragma unroll
  for (int m = 1; m < 16; m <<= 1) {
#pragma unroll
    for (int j = 0; j < 4; j++) p[j] += __shfl_xor(p[j], m);
  }
  if (lr == 0) {
#pragma unroll
    for (int j = 0; j < 4; j++) {
      int row = rowb + j;
      if (row < M) a_s[(size_t)row * 4 + h] = p[j];
    }
  }
}

// ---------------- GCN aggregation: CSR gather, wave/dst + ILP-8 ----------------
// FIN 1: out = x1 row f16; FIN 2: out = att row (8 scores fp32)
template <int FIN>
__global__ __launch_bounds__(256) void k_gather(const __half* __restrict__ hh,
                                                const int* __restrict__ rowptr,
                                                const int* __restrict__ adj,
                                                const float* __restrict__ dis,
                                                const float* __restrict__ b,
                                                const float* __restrict__ watt,
                                                void* __restrict__ outv, int n) {
  int wid = threadIdx.x >> 6;
  int lane = threadIdx.x & 63;
  int d = blockIdx.x * 4 + wid;
  if (d >= n) return;
  int p0 = rowptr[d], p1 = rowptr[d + 1];
  int c = lane * 2;
  float2 s;
  {
    unsigned v = *(const unsigned*)&hh[(size_t)d * 128 + c];  // self loop
    s = __half22float2(*(__half2*)&v);
  }
  for (int base = p0; base < p1; base += 64) {
    int remain = p1 - base;
    int m = remain < 64 ? remain : 64;
    int idx = (lane < m) ? adj[base + lane] : 0;
    int j = 0;
    for (; j + 8 <= m; j += 8) {
      int nb[8];
      unsigned v[8];
#pragma unroll
      for (int u = 0; u < 8; u++) nb[u] = __shfl(idx, j + u);
#pragma unroll
      for (int u = 0; u < 8; u++) v[u] = *(const unsigned*)&hh[(size_t)nb[u] * 128 + c];
#pragma unroll
      for (int u = 0; u < 8; u++) {
        float2 f = __half22float2(*(__half2*)&v[u]);
        s.x += f.x;
        s.y += f.y;
      }
    }
    for (; j + 4 <= m; j += 4) {
      int nb[4];
      unsigned v[4];
#pragma unroll
      for (int u = 0; u < 4; u++) nb[u] = __shfl(idx, j + u);
#pragma unroll
      for (int u = 0; u < 4; u++) v[u] = *(const unsigned*)&hh[(size_t)nb[u] * 128 + c];
#pragma unroll
      for (int u = 0; u < 4; u++) {
        float2 f = __half22float2(*(__half2*)&v[u]);
        s.x += f.x;
        s.y += f.y;
      }
    }
    for (; j < m; j++) {
      int nb = __shfl(idx, j);
      unsigned v = *(const unsigned*)&hh[(size_t)nb * 128 + c];
      float2 f = __half22float2(*(__half2*)&v);
      s.x += f.x;
      s.y += f.y;
    }
  }
  float dd = dis[d];
  float x0 = fmaxf(dd * s.x + b[c], 0.f);
  float x1v = fmaxf(dd * s.y + b[c + 1], 0.f);
  if (FIN == 1) {
    __half* o = (__half*)outv;
    __half2 hv = __floats2half2_rn(x0, x1v);
    *(__half2*)&o[(size_t)d * 128 + c] = hv;
  } else {
    float* o = (float*)outv;
    float p[8];
    const float* w0 = &watt[c * 8];
#pragma unroll
    for (int h = 0; h < 8; h++) p[h] = x0 * w0[h] + x1v * w0[8 + h];
#pragma unroll
    for (int mm = 32; mm; mm >>= 1) {
#pragma unroll
      for (int h = 0; h < 8; h++) p[h] += __shfl_xor(p[h], mm);
    }
    if (lane == 0) {
      *(float4*)&o[(size_t)d * 8] = make_float4(p[0], p[1], p[2], p[3]);
      *(float4*)&o[(size_t)d * 8 + 4] = make_float4(p[4], p[5], p[6], p[7]);
    }
  }
}

// ---------------- GAT softmax pass A: denom by dst-gather (regions at NG, 2NG) ----------------
__global__ __launch_bounds__(256) void k_edgeA(const int* __restrict__ rowptr,
                                               const int* __restrict__ adj,
                                               const float* __restrict__ a_s_d,
                                               const float* __restrict__ a_s_c,
                                               const float* __restrict__ att,
                                               float* __restrict__ denom_d,
                                               float* __restrict__ denom_c) {
  int nb1 = (NG + 255) >> 8;
  int blk = blockIdx.x;
  int q = blk >= nb1;
  int d = (blk - (q ? nb1 : 0)) * 256 + threadIdx.x;
  if (d >= NG) return;
  const int* rp = rowptr + NG + (q ? NG : 0);
  const float* a_s = q ? a_s_c : a_s_d;
  float* den = q ? denom_c : denom_d;
  int p0 = rp[d], p1 = rp[d + 1];
  float4 ad4 = *(const float4*)&att[(size_t)d * 8 + q * 4];
  float4 acc = make_float4(0.f, 0.f, 0.f, 0.f);
  for (int p = p0; p < p1; p++) {
    int s = adj[p];
    float4 as4 = *(const float4*)&a_s[(size_t)s * 4];
    float v0 = as4.x + ad4.x, v1 = as4.y + ad4.y, v2 = as4.z + ad4.z, v3 = as4.w + ad4.w;
    v0 = v0 > 0.f ? v0 : 0.2f * v0;
    v1 = v1 > 0.f ? v1 : 0.2f * v1;
    v2 = v2 > 0.f ? v2 : 0.2f * v2;
    v3 = v3 > 0.f ? v3 : 0.2f * v3;
    acc.x += __expf(fminf(v0, 50.f));
    acc.y += __expf(fminf(v1, 50.f));
    acc.z += __expf(fminf(v2, 50.f));
    acc.w += __expf(fminf(v3, 50.f));
  }
  *(float4*)&den[(size_t)d * 4] = acc;
}

// ---------------- GAT softmax pass B: wsrc by src-gather (regions at 3NG, 3NG+NDR) ----------------
__global__ __launch_bounds__(256) void k_edgeB(const int* __restrict__ rowptr,
                                               const int* __restrict__ adj,
                                               const float* __restrict__ a_s_d,
                                               const float* __restrict__ a_s_c,
                                               const float* __restrict__ att,
                                               const float* __restrict__ denom_d,
                                               const float* __restrict__ denom_c,
                                               float* __restrict__ wsrc_d,
                                               float* __restrict__ wsrc_c) {
  int gw = (blockIdx.x * 256 + threadIdx.x) >> 6;
  int lane = threadIdx.x & 63;
  int q = gw >= NDR;
  int s = q ? gw - NDR : gw;
  if (q && s >= NDI) return;
  const int* rp = rowptr + 3 * NG + (q ? NDR : 0);
  const float* a_s = q ? a_s_c : a_s_d;
  const float* den = q ? denom_c : denom_d;
  float* ws = q ? wsrc_c : wsrc_d;
  int p0 = rp[s], p1 = rp[s + 1];
  float4 as4 = *(const float4*)&a_s[(size_t)s * 4];
  int attoff = q * 4;
  float4 acc = make_float4(0.f, 0.f, 0.f, 0.f);
  for (int p = p0 + lane; p < p1; p += 64) {
    int d = adj[p];
    float4 ad4 = *(const float4*)&att[(size_t)d * 8 + attoff];
    float4 dn = *(const float4*)&den[(size_t)d * 4];
    float v0 = as4.x + ad4.x, v1 = as4.y + ad4.y, v2 = as4.z + ad4.z, v3 = as4.w + ad4.w;
    v0 = v0 > 0.f ? v0 : 0.2f * v0;
    v1 = v1 > 0.f ? v1 : 0.2f * v1;
    v2 = v2 > 0.f ? v2 : 0.2f * v2;
    v3 = v3 > 0.f ? v3 : 0.2f * v3;
    acc.x += __expf(fminf(v0, 50.f)) / (dn.x + 1e-16f);
    acc.y += __expf(fminf(v1, 50.f)) / (dn.y + 1e-16f);
    acc.z += __expf(fminf(v2, 50.f)) / (dn.z + 1e-16f);
    acc.w += __expf(fminf(v3, 50.f)) / (dn.w + 1e-16f);
  }
#pragma unroll
  for (int m = 1; m < 64; m <<= 1) {
    acc.x += __shfl_xor(acc.x, m);
    acc.y += __shfl_xor(acc.y, m);
    acc.z += __shfl_xor(acc.z, m);
    acc.w += __shfl_xor(acc.w, m);
  }
  if (lane == 0) *(float4*)&ws[(size_t)s * 4] = acc;
}

// ---------------- fused weighted column sums + embedding column sums ----------------
__global__ __launch_bounds__(512) void k_sum(const __half* __restrict__ hs_d,
                                             const float* __restrict__ wsrc_d,
                                             float* __restrict__ S_d,
                                             const __half* __restrict__ hs_c,
                                             const float* __restrict__ wsrc_c,
                                             float* __restrict__ S_c,
                                             const float* __restrict__ xd,
                                             float* __restrict__ od,
                                             const float* __restrict__ xc,
                                             float* __restrict__ oc) {
  int t = threadIdx.x;
  const int nws_d = (NDR + 63) >> 6;       // 157
  const int nws_c = (NDI + 63) >> 6;       // 79
  const int ncs_d = (NDR + 511) >> 9;      // 20
  int blk = blockIdx.x;
  if (blk < nws_d + nws_c) {
    int q = blk >= nws_d;
    const __half* hs = q ? hs_c : hs_d;
    const float* wsrc = q ? wsrc_c : wsrc_d;
    float* S = q ? S_c : S_d;
    int N = q ? NDI : NDR;
    int r0 = (q ? blk - nws_d : blk) * 64;
    int h = t >> 7;
    int r1 = min(r0 + 64, N);
    float acc = 0.f;
    for (int r = r0; r < r1; r++) acc += wsrc[r * 4 + h] * __half2float(hs[(size_t)r * 512 + t]);
    atomAddF(&S[t], acc);
  } else {
    int cb = blk - nws_d - nws_c;
    int q = cb >= ncs_d;
    const float* x = q ? xc : xd;
    float* o = q ? oc : od;
    int N = q ? NDI : NDR;
    int r0 = (q ? cb - ncs_d : cb) * 512 + (t >> 7) * 128;
    int col = t & 127;
    int r1 = min(r0 + 128, N);
    float acc = 0.f;
    for (int r = r0; r < r1; r++) acc += x[(size_t)r * 128 + col];
    if (acc != 0.f || r0 < N) atomAddF(&o[col], acc);
  }
}

// ---------------- final fuse ----------------
__global__ __launch_bounds__(128) void k_final(const float* __restrict__ S_d,
                                               const float* __restrict__ S_c,
                                               const float* __restrict__ bdsum,
                                               const float* __restrict__ bcsum,
                                               const float* __restrict__ bd_bias,
                                               const float* __restrict__ bc_bias,
                                               const float* __restrict__ fuse_w,
                                               const float* __restrict__ fuse_b,
                                               float* __restrict__ out) {
  __shared__ float cat[384];
  int t = threadIdx.x;
  float sd = S_d[t] + S_d[128 + t] + S_d[256 + t] + S_d[384 + t];
  float sc = S_c[t] + S_c[128 + t] + S_c[256 + t] + S_c[384 + t];
  const float inv = 1.0f / (4.0f * (float)NG);
  cat[t] = 0.5f * (sd * inv + bd_bias[t] + sc * inv + bc_bias[t]);
  cat[128 + t] = bdsum[t] * (1.0f / (float)NDR);
  cat[256 + t] = bcsum[t] * (1.0f / (float)NDI);
  __syncthreads();
  float o = fuse_b[t];
  for (int k = 0; k < 384; k++) o += cat[k] * fuse_w[k * 128 + t];
  out[t] = o;
}

// ---------------- host launch ----------------
extern "C" void kernel_launch(void* const* d_in, const int* in_sizes, int n_in,
                              void* d_out, int out_size, void* d_ws, size_t ws_size,
                              hipStream_t stream) {
  const float* gene_nodes   = (const float*)d_in[0];
  const int*   drug_edges   = (const int*)d_in[1];
  const int*   dise_edges   = (const int*)d_in[2];
  const int*   gene_edges   = (const int*)d_in[3];
  const float* gcn1_w       = (const float*)d_in[4];
  const float* gcn1_b       = (const float*)d_in[5];
  const float* gcn2_w       = (const float*)d_in[6];
  const float* gcn2_b       = (const float*)d_in[7];
  const float* drug_embed   = (const float*)d_in[8];
  const float* dise_embed   = (const float*)d_in[9];
  const float* gat_d_w      = (const float*)d_in[10];
  const float* gat_d_att_s  = (const float*)d_in[11];
  const float* gat_d_att_d  = (const float*)d_in[12];
  const float* gat_d_b      = (const float*)d_in[13];
  const float* gat_c_w      = (const float*)d_in[14];
  const float* gat_c_att_s  = (const float*)d_in[15];
  const float* gat_c_att_d  = (const float*)d_in[16];
  const float* gat_c_b      = (const float*)d_in[17];
  const float* fuse_w       = (const float*)d_in[18];
  const float* fuse_b       = (const float*)d_in[19];
  const int Ed = in_sizes[1] / 2;
  const int Ec = in_sizes[2] / 2;
  const int Eg = in_sizes[3] / 2;
  float* out = (float*)d_out;
  (void)n_in; (void)out_size; (void)ws_size;

  const int NDOM = 3 * NG + NDR + NDI;      // 315000 combined degree domain
  const int NBS = cdiv_h(NDOM, 1024);       // 308 scan blocks

  // workspace layout (zero-init region first, single memset)
  char* w = (char*)d_ws;
  auto alloc = [&](size_t n) {
    char* p = w;
    w += (n + 511) & ~(size_t)511;
    return p;
  };
  char* z0 = w;
  unsigned* deg     = (unsigned*)alloc((size_t)NDOM * 4);
  float* S_d        = (float*)alloc(512 * 4);
  float* S_c        = (float*)alloc(512 * 4);
  float* bdsum      = (float*)alloc(512);
  float* bcsum      = (float*)alloc(512);
  size_t zbytes = (size_t)(w - z0);
  float* denom_d    = (float*)alloc((size_t)NG * 16);
  float* denom_c    = (float*)alloc((size_t)NG * 16);
  float* wsrc_d     = (float*)alloc((size_t)NDR * 16);
  float* wsrc_c     = (float*)alloc((size_t)NDI * 16);
  float* dis        = (float*)alloc((size_t)NG * 4);
  float* watt       = (float*)alloc(128 * 8 * 4);
  float* att        = (float*)alloc((size_t)NG * 8 * 4);
  float* a_s_d      = (float*)alloc((size_t)NDR * 16);
  float* a_s_c      = (float*)alloc((size_t)NDI * 16);
  unsigned* partial = (unsigned*)alloc((size_t)512 * 4);
  int* rowptr       = (int*)alloc((size_t)(NDOM + 1) * 4);
  int* cursor       = (int*)alloc((size_t)NDOM * 4);
  int* adj          = (int*)alloc((size_t)(Eg + 2 * (Ed + Ec)) * 4);
  __half* Wt1       = (__half*)alloc((size_t)128 * 128 * 2);
  __half* Wt2       = (__half*)alloc((size_t)128 * 128 * 2);
  __half* Wtd       = (__half*)alloc((size_t)512 * 128 * 2);
  __half* Wtc       = (__half*)alloc((size_t)512 * 128 * 2);
  __half* hh        = (__half*)alloc((size_t)NG * 128 * 2);
  __half* x1        = (__half*)alloc((size_t)NG * 128 * 2);
  __half* hs_d      = (__half*)alloc((size_t)NDR * 512 * 2);
  __half* hs_c      = (__half*)alloc((size_t)NDI * 512 * 2);

  hipMemsetAsync(z0, 0, zbytes, stream);

  // combined CSR build (gene + both bipartite directions) + weight prep
  int nbe = cdiv_h(Eg, 256) + cdiv_h(Ed, 256) + cdiv_h(Ec, 256);
  k_degAll<<<nbe, 256, 0, stream>>>(gene_edges, Eg, drug_edges, Ed, dise_edges, Ec, deg);
  k_blocksum4<<<NBS, 256, 0, stream>>>(deg, partial, NDOM);
  k_scanpart<<<1, 512, 0, stream>>>(partial, NBS);
  k_rowptrAll<<<NBS, 256, 0, stream>>>(deg, partial, NDOM, rowptr, cursor, dis);
  k_fillAll<<<nbe, 256, 0, stream>>>(gene_edges, Eg, drug_edges, Ed, dise_edges, Ec, cursor, adj);
  k_prep<<<11, 256, 0, stream>>>(gcn1_w, gcn2_w, gat_d_w, gat_c_w, gat_d_att_d, gat_c_att_d,
                                 Wt1, Wt2, Wtd, Wtc, watt);

  // GCN layer 1
  k_mgemm<0><<<cdiv_h(NG, 64), 256, 0, stream>>>(gene_nodes, Wt1, NG, dis, hh);
  k_gather<1><<<cdiv_h(NG, 4), 256, 0, stream>>>(hh, rowptr, adj, dis, gcn1_b, nullptr, x1, NG);

  // GCN layer 2 (f16 input; att-score epilogue; x2 never materialized)
  k_mgemm<1><<<cdiv_h(NG, 64), 256, 0, stream>>>(x1, Wt2, NG, dis, hh);
  k_gather<2><<<cdiv_h(NG, 4), 256, 0, stream>>>(hh, rowptr, adj, dis, gcn2_b, watt, att, NG);

  // GAT source transforms (both graphs, one launch)
  k_mgat<<<dim3(cdiv_h(NDR, 64) + cdiv_h(NDI, 64), 4), 256, 0, stream>>>(
      drug_embed, dise_embed, Wtd, Wtc, gat_d_att_s, gat_c_att_s, hs_d, hs_c, a_s_d, a_s_c);

  // GAT softmax: denom by dst-gather, wsrc by src-gather (no atomics)
  k_edgeA<<<2 * cdiv_h(NG, 256), 256, 0, stream>>>(rowptr, adj, a_s_d, a_s_c, att, denom_d, denom_c);
  k_edgeB<<<cdiv_h((NDR + NDI) * 64, 256), 256, 0, stream>>>(rowptr, adj, a_s_d, a_s_c, att,
                                                             denom_d, denom_c, wsrc_d, wsrc_c);

  // fused weighted column sums + embedding means
  int nsum = (cdiv_h(NDR, 64) + cdiv_h(NDI, 64)) + (cdiv_h(NDR, 512) + cdiv_h(NDI, 512));
  k_sum<<<nsum, 512, 0, stream>>>(hs_d, wsrc_d, S_d, hs_c, wsrc_c, S_c,
                                  drug_embed, bdsum, dise_embed, bcsum);

  // final fuse
  k_final<<<1, 128, 0, stream>>>(S_d, S_c, bdsum, bcsum, gat_d_b, gat_c_b, fuse_w, fuse_b, out);
}